// Round 1
// 838.954 us; speedup vs baseline: 1.0475x; 1.0475x over previous
//
#include <hip/hip_runtime.h>
#include <stdint.h>

// DeepSpeed self-attention forward, bf16-MFMA implementation.
// B=2, S=1024, H=4096, NH=32, HD=128. All matmuls via mfma_f32_16x16x32_bf16.
// Round 4: both big GEMMs moved to an 8-wave 128x256 pipelined structure
// (T2 LDS swizzle + T3/T4 counted-vmcnt phases + T5 setprio + T1 XCD swizzle).

#define S_LEN 1024
#define HID   4096
#define NHEAD 32
#define HDIM  128

typedef __attribute__((ext_vector_type(8))) short bf16x8;   // 8 bf16 (4 VGPRs)
typedef __attribute__((ext_vector_type(4))) float f32x4;    // MFMA C/D
typedef __attribute__((ext_vector_type(8))) unsigned short us8; // 16B store

__device__ __forceinline__ unsigned short f2bf(float f) {
    union { float f; unsigned u; } v; v.f = f;
    unsigned r = v.u + 0x7fffu + ((v.u >> 16) & 1u);
    return (unsigned short)(r >> 16);
}

__device__ __forceinline__ void gld16(const unsigned short* g, unsigned short* l) {
    __builtin_amdgcn_global_load_lds(
        (const __attribute__((address_space(1))) void*)g,
        (__attribute__((address_space(3))) void*)l, 16, 0, 0);
}

// ---------------- LayerNorm + bf16 cast: x[2048][4096] -> inp_norm bf16 ----------
__global__ __launch_bounds__(256) void ln_kernel(const float* __restrict__ x,
        const float* __restrict__ w, const float* __restrict__ bch,
        unsigned short* __restrict__ out) {
    const int row = blockIdx.x;
    const int t = threadIdx.x;
    const float* xr = x + (size_t)row * HID;
    float4 v[4];
    float sum = 0.f, sq = 0.f;
#pragma unroll
    for (int i = 0; i < 4; i++) {
        v[i] = ((const float4*)xr)[t + (i << 8)];
        sum += v[i].x + v[i].y + v[i].z + v[i].w;
        sq  += v[i].x*v[i].x + v[i].y*v[i].y + v[i].z*v[i].z + v[i].w*v[i].w;
    }
#pragma unroll
    for (int off = 32; off; off >>= 1) {
        sum += __shfl_down(sum, off);
        sq  += __shfl_down(sq, off);
    }
    __shared__ float ssum[4], ssq[4];
    if ((t & 63) == 0) { ssum[t >> 6] = sum; ssq[t >> 6] = sq; }
    __syncthreads();
    const float s_all = ssum[0] + ssum[1] + ssum[2] + ssum[3];
    const float q_all = ssq[0] + ssq[1] + ssq[2] + ssq[3];
    const float mean = s_all * (1.f / HID);
    const float var  = q_all * (1.f / HID) - mean * mean;
    const float rstd = rsqrtf(var + 1e-5f);
    unsigned short* orow = out + (size_t)row * HID;
#pragma unroll
    for (int i = 0; i < 4; i++) {
        float4 wv = ((const float4*)w)[t + (i << 8)];
        float4 bv = ((const float4*)bch)[t + (i << 8)];
        ushort4 o;
        o.x = f2bf((v[i].x - mean) * rstd * wv.x + bv.x);
        o.y = f2bf((v[i].y - mean) * rstd * wv.y + bv.y);
        o.z = f2bf((v[i].z - mean) * rstd * wv.z + bv.z);
        o.w = f2bf((v[i].w - mean) * rstd * wv.w + bv.w);
        ((ushort4*)orow)[t + (i << 8)] = o;
    }
}

// ------------- transpose + fp32->bf16: W[K][N] -> Wt[N][K] ----------------------
__global__ __launch_bounds__(256) void transconv(const float* __restrict__ W,
        unsigned short* __restrict__ Wt, int K, int N) {
    __shared__ float tileT[128 * 65];   // [n][k], pad 65 (33.3 KB)
    const int n0 = blockIdx.x << 7, k0 = blockIdx.y << 6;
    const int t = threadIdx.x;
#pragma unroll
    for (int it = 0; it < 8; it++) {
        int idx = (it << 8) + t;
        int r = idx >> 5;            // k row 0..63
        int c4 = idx & 31;           // float4 column 0..31
        float4 v = *(const float4*)(W + (size_t)(k0 + r) * N + n0 + (c4 << 2));
        tileT[((c4 << 2) + 0) * 65 + r] = v.x;
        tileT[((c4 << 2) + 1) * 65 + r] = v.y;
        tileT[((c4 << 2) + 2) * 65 + r] = v.z;
        tileT[((c4 << 2) + 3) * 65 + r] = v.w;
    }
    __syncthreads();
#pragma unroll
    for (int it = 0; it < 4; it++) {
        int idx = (it << 8) + t;
        int n = idx >> 3;            // 0..127
        int k8 = idx & 7;            // ushort8 column, 0..7 (8 k each)
        const float* src = &tileT[n * 65 + (k8 << 3)];
        us8 o;
#pragma unroll
        for (int e = 0; e < 8; e++) o[e] = f2bf(src[e]);
        *(us8*)(Wt + (size_t)(n0 + n) * K + k0 + (k8 << 3)) = o;
    }
}

// =================================================================================
// Pipelined 128x256 GEMM core. 512 threads = 8 waves (2M x 4N), BK=64.
// K hardcoded 4096 (NT=64 K-tiles).
//
// LDS: 3 rotating buffers x { A: 2x[128][32], B: 2x[256][32] } bf16 = 144 KB.
// Schedule per K-tile (2 phases, ks=0/1):
//   phase: 8x ds_read_b128 (4 A-frags + 4 B-frags, XOR-swizzled)
//          3x global_load_lds (A-ks:1 + B-ks:2) for tile t+2 -> idle buffer
//          s_barrier; lgkmcnt(0); setprio(1); 16x MFMA; setprio(0)
//          [phase ks=1 only] s_waitcnt vmcnt(6)   <- counted, never 0 in loop
//          s_barrier
// vmcnt(6): the 6 newest loads (tile t+2) may stay in flight; everything for
// tile t+1 (issued during tile t-1, ~3 phases ago) is forced complete.
//
// Swizzle (rule 21, both-sides): LDS stays linear for global_load_lds; the
// GLOBAL source chunk is pre-permuted with chunk ^= (row>>1)&3, and ds_read
// applies the same involution -> fragment reads hit all 8 bank-quads
// (2 lanes/bank = free) instead of the unswizzled 8-way pattern.
// =================================================================================

#define GEMM_PHASE(CB, KS, PFT, PFB, DO_VM)                                       \
  {                                                                               \
    bf16x8 af[4], bfv[4];                                                         \
    _Pragma("unroll") for (int ii = 0; ii < 4; ii++) af[ii] = ldA(CB, KS, ii);    \
    _Pragma("unroll") for (int jj = 0; jj < 4; jj++) bfv[jj] = ldB(CB, KS, jj);   \
    stageA(PFT, KS, PFB);                                                         \
    stageB(PFT, KS, PFB);                                                         \
    __builtin_amdgcn_s_barrier();                                                 \
    asm volatile("s_waitcnt lgkmcnt(0)" ::: "memory");                            \
    __builtin_amdgcn_sched_barrier(0);                                            \
    __builtin_amdgcn_s_setprio(1);                                                \
    _Pragma("unroll") for (int ii = 0; ii < 4; ii++)                              \
      _Pragma("unroll") for (int jj = 0; jj < 4; jj++)                            \
        acc[ii][jj] = __builtin_amdgcn_mfma_f32_16x16x32_bf16(                    \
            af[ii], bfv[jj], acc[ii][jj], 0, 0, 0);                               \
    __builtin_amdgcn_s_setprio(0);                                                \
    if (DO_VM) asm volatile("s_waitcnt vmcnt(6)" ::: "memory");                   \
    __builtin_amdgcn_s_barrier();                                                 \
  }

#define GEMM_TILE(TT, CB)                                                         \
  {                                                                               \
    int pf_ = (TT) + 2; if (pf_ > 63) pf_ = 63;                                   \
    GEMM_PHASE(CB, 0, pf_, ((CB) + 2) % 3, 0)                                     \
    GEMM_PHASE(CB, 1, pf_, ((CB) + 2) % 3, 1)                                     \
  }

__device__ __forceinline__ void gemm_core_8w(
        const unsigned short* __restrict__ GA,   // A panel base row (bm*128), [.][4096]
        const unsigned short* __restrict__ GB,   // B panel base row (bn*256), [.][4096]
        unsigned short* lds,                     // 73728 ushorts (144 KB)
        f32x4 acc[4][4]) {
    const int t = threadIdx.x;
    const int wave = t >> 6, lane = t & 63, quad = lane >> 4, l16 = lane & 15;
    const int waveM = wave >> 2, waveN = wave & 3;
    const int srow = lane >> 2;                               // 0..15 in 16-row group
    const int scol = (((lane & 3) ^ ((lane >> 3) & 3)) << 3); // pre-swizzled src col

    // A sub-tile ks: 128x32 = 4096 el at buf*24576 + ks*4096; 8 x 1KB issues (1/wave)
    auto stageA = [&](int tau, int ks, int buf) {
        const int row = (wave << 4) + srow;                   // 0..127
        gld16(GA + ((size_t)row << 12) + (tau << 6) + (ks << 5) + scol,
              lds + buf * 24576 + (ks << 12) + (wave << 9));
    };
    // B sub-tile ks: 256x32 = 8192 el at buf*24576 + 8192 + ks*8192; 16 issues (2/wave)
    auto stageB = [&](int tau, int ks, int buf) {
#pragma unroll
        for (int u = 0; u < 2; u++) {
            const int ii = (wave << 1) + u;
            const int row = (ii << 4) + srow;                 // 0..255
            gld16(GB + ((size_t)row << 12) + (tau << 6) + (ks << 5) + scol,
                  lds + buf * 24576 + 8192 + (ks << 13) + (ii << 9));
        }
    };
    auto ldA = [&](int buf, int ks, int ii) -> bf16x8 {
        const int r = (waveM << 6) + (ii << 4) + l16;         // 0..127
        return ((const bf16x8*)(lds + buf * 24576 + (ks << 12)))
            [(r << 2) + (quad ^ ((r >> 1) & 3))];
    };
    auto ldB = [&](int buf, int ks, int jj) -> bf16x8 {
        const int r = (waveN << 6) + (jj << 4) + l16;         // 0..255
        return ((const bf16x8*)(lds + buf * 24576 + 8192 + (ks << 13)))
            [(r << 2) + (quad ^ ((r >> 1) & 3))];
    };

    // prologue: tile0 -> buf0 (6 issues), tile1 -> buf1 (6 issues); drain tile0.
    stageA(0, 0, 0); stageB(0, 0, 0); stageA(0, 1, 0); stageB(0, 1, 0);
    stageA(1, 0, 1); stageB(1, 0, 1); stageA(1, 1, 1); stageB(1, 1, 1);
    asm volatile("s_waitcnt vmcnt(6)" ::: "memory");
    __builtin_amdgcn_s_barrier();

    // 64 K-tiles; literal buffer index per body so LDS bases const-fold.
    for (int tb = 0; tb < 63; tb += 3) {
        GEMM_TILE(tb,     0)
        GEMM_TILE(tb + 1, 1)
        GEMM_TILE(tb + 2, 2)
    }
    GEMM_TILE(63, 0)
    asm volatile("s_waitcnt vmcnt(0)" ::: "memory");   // drain dangling prefetches
}

// ---------------- QKV GEMM: A[2048][4096] x Bt[12288][4096] + bias, scatter -----
// Grid 768 = 16 bm x 48 bn = exactly 3 x 256 CUs. XCD swizzle: orig%8 -> XCD,
// bm = {2x,2x+1} per XCD so the 1MB A-panels stay L2-resident, B streams via L3.
__global__ __launch_bounds__(512, 2) void gemm_qkv8(
        const unsigned short* __restrict__ A,
        const unsigned short* __restrict__ Bt,
        const float* __restrict__ bias,
        unsigned short* __restrict__ qb,
        unsigned short* __restrict__ kb,
        unsigned short* __restrict__ vt) {
    __shared__ unsigned short lds[73728];
    const int orig = blockIdx.x;
    const int wg = ((orig & 7) * 96) + (orig >> 3);
    const int bm = wg / 48, bn = wg - bm * 48;
    const int t = threadIdx.x;
    const int wave = t >> 6, lane = t & 63, quad = lane >> 4, l16 = lane & 15;
    const int waveM = wave >> 2, waveN = wave & 3;

    const f32x4 fz = {0.f, 0.f, 0.f, 0.f};
    f32x4 acc[4][4];
#pragma unroll
    for (int i = 0; i < 4; i++)
#pragma unroll
        for (int j = 0; j < 4; j++) acc[i][j] = fz;

    gemm_core_8w(A + ((size_t)bm << 19), Bt + ((size_t)bn << 20), lds, acc);

    const int nbase = (bn << 8) + (waveN << 6);
    const int which = nbase >> 12;           // 0=q 1=k 2=v (wave-uniform)
#pragma unroll
    for (int ii = 0; ii < 4; ii++) {
#pragma unroll
        for (int jj = 0; jj < 4; jj++) {
#pragma unroll
            for (int r = 0; r < 4; r++) {
                int m = (bm << 7) + (waveM << 6) + (ii << 4) + (quad << 2) + r;
                int n = nbase + (jj << 4) + l16;
                float v = acc[ii][jj][r] + bias[n];
                unsigned short bvv = f2bf(v);
                int bb = m >> 10, s = m & 1023;
                int h = n & 4095, head = h >> 7, hd = h & 127;
                size_t bh = (size_t)(bb << 5) + head;
                if (which == 0)      qb[(bh * S_LEN + s) * HDIM + hd] = bvv;
                else if (which == 1) kb[(bh * S_LEN + s) * HDIM + hd] = bvv;
                else                 vt[(bh * HDIM + hd) * S_LEN + s] = bvv;
            }
        }
    }
}

// ---------------- proj GEMM: ctx[2048][4096] x ow_t[4096][4096] -> fp32 out ------
// Grid 256 = 16 x 16 = exactly 1 round of 256 CUs.
__global__ __launch_bounds__(512, 2) void gemm_proj8(
        const unsigned short* __restrict__ A,
        const unsigned short* __restrict__ Bt,
        float* __restrict__ outf) {
    __shared__ unsigned short lds[73728];
    const int orig = blockIdx.x;
    const int wg = ((orig & 7) * 32) + (orig >> 3);
    const int bm = wg >> 4, bn = wg & 15;
    const int t = threadIdx.x;
    const int wave = t >> 6, lane = t & 63, quad = lane >> 4, l16 = lane & 15;
    const int waveM = wave >> 2, waveN = wave & 3;

    const f32x4 fz = {0.f, 0.f, 0.f, 0.f};
    f32x4 acc[4][4];
#pragma unroll
    for (int i = 0; i < 4; i++)
#pragma unroll
        for (int j = 0; j < 4; j++) acc[i][j] = fz;

    gemm_core_8w(A + ((size_t)bm << 19), Bt + ((size_t)bn << 20), lds, acc);

#pragma unroll
    for (int ii = 0; ii < 4; ii++)
#pragma unroll
        for (int jj = 0; jj < 4; jj++)
#pragma unroll
            for (int r = 0; r < 4; r++) {
                int m = (bm << 7) + (waveM << 6) + (ii << 4) + (quad << 2) + r;
                int n = (bn << 8) + (waveN << 6) + (jj << 4) + l16;
                outf[((size_t)m << 12) + n] = acc[ii][jj][r];
            }
}

// ---------------- flash attention: 64-query tile per block, causal ---------------
__global__ __launch_bounds__(256) void attn_kernel(
        const unsigned short* __restrict__ qbuf,   // [64][1024][128]
        const unsigned short* __restrict__ kbuf,   // [64][1024][128]
        const unsigned short* __restrict__ vtbuf,  // [64][128][1024]
        const float* __restrict__ mask,            // [2][1024]
        unsigned short* __restrict__ ctx) {        // [2048][4096]
    __shared__ unsigned short q_lds[64 * 128];
    __shared__ unsigned short k_lds[64 * 128];
    __shared__ unsigned short v_lds[128 * 64];     // [hd][key]
    __shared__ unsigned short p_lds[64 * 64];
    const int t = threadIdx.x;
    const int wave = t >> 6, lane = t & 63, quad = lane >> 4, l16 = lane & 15;
    const int bq = blockIdx.x, bh = blockIdx.y;
    const int q0 = bq << 6;
    const int b = bh >> 5;
    const unsigned short* Q  = qbuf  + (size_t)bh * S_LEN * HDIM;
    const unsigned short* Kp = kbuf  + (size_t)bh * S_LEN * HDIM;
    const unsigned short* Vp = vtbuf + (size_t)bh * HDIM * S_LEN;

    {
        int r = t >> 4, c = (t & 15) << 3;
#pragma unroll
        for (int it = 0; it < 4; it++)
            gld16(Q + (size_t)(q0 + r + (it << 4)) * HDIM + c,
                  q_lds + ((((it << 8) + (wave << 6))) << 3));
    }

    const f32x4 fz = {0.f, 0.f, 0.f, 0.f};
    f32x4 o[8];
#pragma unroll
    for (int n = 0; n < 8; n++) o[n] = fz;
    float l_i[4] = {0.f, 0.f, 0.f, 0.f};
    const float scale = 0.08838834764831845f;   // 1/sqrt(128)
    const float* mrow = mask + b * S_LEN;

    for (int kt = 0; kt <= bq; kt++) {
        const int k0 = kt << 6;
        {
            int rk = t >> 4, ck = (t & 15) << 3;
            int rv = t >> 3, cv = (t & 7) << 3;
#pragma unroll
            for (int it = 0; it < 4; it++) {
                gld16(Kp + (size_t)(k0 + rk + (it << 4)) * HDIM + ck,
                      k_lds + (((it << 8) + (wave << 6)) << 3));
                gld16(Vp + (size_t)(rv + (it << 5)) * S_LEN + k0 + cv,
                      v_lds + (((it << 8) + (wave << 6)) << 3));
            }
        }
        __syncthreads();

        f32x4 sacc[4];
#pragma unroll
        for (int j = 0; j < 4; j++) sacc[j] = fz;
        const bf16x8* qv = (const bf16x8*)q_lds;
        const bf16x8* kv = (const bf16x8*)k_lds;
#pragma unroll
        for (int kk = 0; kk < 4; kk++) {
            bf16x8 aq = qv[(((wave << 4) + l16) << 4) + (kk << 2) + quad];
#pragma unroll
            for (int j = 0; j < 4; j++) {
                bf16x8 bk = kv[((((j << 4) + l16)) << 4) + (kk << 2) + quad];
                sacc[j] = __builtin_amdgcn_mfma_f32_16x16x32_bf16(aq, bk, sacc[j], 0, 0, 0);
            }
        }

#pragma unroll
        for (int r = 0; r < 4; r++) {
            int qrow = q0 + (wave << 4) + (quad << 2) + r;
#pragma unroll
            for (int j = 0; j < 4; j++) {
                int key = k0 + (j << 4) + l16;
                float x = sacc[j][r] * scale + mrow[key];
                if (key > qrow) x -= 10000.0f;
                float p = __expf(x);
                l_i[r] += p;
                p_lds[((wave << 4) + (quad << 2) + r) * 64 + (j << 4) + l16] = f2bf(p);
            }
        }
        __syncthreads();

        const bf16x8* pvv = (const bf16x8*)p_lds;
        const bf16x8* vv = (const bf16x8*)v_lds;
#pragma unroll
        for (int ks = 0; ks < 2; ks++) {
            bf16x8 ap = pvv[(((wave << 4) + l16) << 3) + (ks << 2) + quad];
#pragma unroll
            for (int n = 0; n < 8; n++) {
                bf16x8 bvv = vv[((((n << 4) + l16)) << 3) + (ks << 2) + quad];
                o[n] = __builtin_amdgcn_mfma_f32_16x16x32_bf16(ap, bvv, o[n], 0, 0, 0);
            }
        }
        __syncthreads();
    }

#pragma unroll
    for (int r = 0; r < 4; r++) {
        float l = l_i[r];
#pragma unroll
        for (int off = 1; off < 16; off <<= 1) l += __shfl_xor(l, off);
        float inv = 1.0f / l;
        int qrow = q0 + (wave << 4) + (quad << 2) + r;
        size_t base = ((size_t)(b * S_LEN + qrow)) * HID + ((size_t)(bh & 31) << 7);
#pragma unroll
        for (int n = 0; n < 8; n++)
            ctx[base + (n << 4) + l16] = f2bf(o[n][r] * inv);
    }
}

extern "C" void kernel_launch(void* const* d_in, const int* in_sizes, int n_in,
                              void* d_out, int out_size, void* d_ws, size_t ws_size,
                              hipStream_t stream) {
    const float* x       = (const float*)d_in[0];
    const float* mask    = (const float*)d_in[1];
    const float* norm_w  = (const float*)d_in[2];
    const float* norm_b  = (const float*)d_in[3];
    const float* qkv_w   = (const float*)d_in[4];
    const float* qkv_b   = (const float*)d_in[5];
    const float* attn_ow = (const float*)d_in[6];
    float* out = (float*)d_out;

    char* ws = (char*)d_ws;
    size_t off = 0;
    auto alloc = [&](size_t bytes) {
        char* p = ws + off;
        off += (bytes + 255) & ~(size_t)255;
        return p;
    };
    unsigned short* inp_norm = (unsigned short*)alloc((size_t)2048 * HID * 2);
    unsigned short* qkv_wt   = (unsigned short*)alloc((size_t)3 * HID * HID * 2);
    unsigned short* ow_t     = (unsigned short*)alloc((size_t)HID * HID * 2);
    unsigned short* qb       = (unsigned short*)alloc((size_t)64 * S_LEN * HDIM * 2);
    unsigned short* kb       = (unsigned short*)alloc((size_t)64 * S_LEN * HDIM * 2);
    unsigned short* vt       = (unsigned short*)alloc((size_t)64 * S_LEN * HDIM * 2);
    unsigned short* ctx      = (unsigned short*)alloc((size_t)2048 * HID * 2);

    ln_kernel<<<2048, 256, 0, stream>>>(x, norm_w, norm_b, inp_norm);
    transconv<<<dim3(3 * HID / 128, HID / 64), 256, 0, stream>>>(qkv_w, qkv_wt, HID, 3 * HID);
    transconv<<<dim3(HID / 128, HID / 64), 256, 0, stream>>>(attn_ow, ow_t, HID, HID);
    gemm_qkv8<<<768, 512, 0, stream>>>(inp_norm, qkv_wt, qkv_b, qb, kb, vt);
    attn_kernel<<<dim3(16, 64), 256, 0, stream>>>(qb, kb, vt, mask, ctx);
    gemm_proj8<<<256, 512, 0, stream>>>(ctx, ow_t, out);
}

// Round 2
// 810.501 us; speedup vs baseline: 1.0843x; 1.0351x over previous
//
#include <hip/hip_runtime.h>
#include <stdint.h>

// DeepSpeed self-attention forward, bf16-MFMA implementation.
// B=2, S=1024, H=4096, NH=32, HD=128. All matmuls via mfma_f32_16x16x32_bf16.
// Round 5: QKV GEMM moved to m201 geometry — 256x256 tile, 8 waves (2Mx4N),
// per-wave 128x64 output, 4 phases/K-tile, 2-buffer LDS (128KB), vmcnt(4)
// counted waits. Proj keeps the 128x256 core (exact 256-block grid fit).

#define S_LEN 1024
#define HID   4096
#define NHEAD 32
#define HDIM  128

typedef __attribute__((ext_vector_type(8))) short bf16x8;   // 8 bf16 (4 VGPRs)
typedef __attribute__((ext_vector_type(4))) float f32x4;    // MFMA C/D
typedef __attribute__((ext_vector_type(8))) unsigned short us8; // 16B store

__device__ __forceinline__ unsigned short f2bf(float f) {
    union { float f; unsigned u; } v; v.f = f;
    unsigned r = v.u + 0x7fffu + ((v.u >> 16) & 1u);
    return (unsigned short)(r >> 16);
}

__device__ __forceinline__ void gld16(const unsigned short* g, unsigned short* l) {
    __builtin_amdgcn_global_load_lds(
        (const __attribute__((address_space(1))) void*)g,
        (__attribute__((address_space(3))) void*)l, 16, 0, 0);
}

// ---------------- LayerNorm + bf16 cast: x[2048][4096] -> inp_norm bf16 ----------
__global__ __launch_bounds__(256) void ln_kernel(const float* __restrict__ x,
        const float* __restrict__ w, const float* __restrict__ bch,
        unsigned short* __restrict__ out) {
    const int row = blockIdx.x;
    const int t = threadIdx.x;
    const float* xr = x + (size_t)row * HID;
    float4 v[4];
    float sum = 0.f, sq = 0.f;
#pragma unroll
    for (int i = 0; i < 4; i++) {
        v[i] = ((const float4*)xr)[t + (i << 8)];
        sum += v[i].x + v[i].y + v[i].z + v[i].w;
        sq  += v[i].x*v[i].x + v[i].y*v[i].y + v[i].z*v[i].z + v[i].w*v[i].w;
    }
#pragma unroll
    for (int off = 32; off; off >>= 1) {
        sum += __shfl_down(sum, off);
        sq  += __shfl_down(sq, off);
    }
    __shared__ float ssum[4], ssq[4];
    if ((t & 63) == 0) { ssum[t >> 6] = sum; ssq[t >> 6] = sq; }
    __syncthreads();
    const float s_all = ssum[0] + ssum[1] + ssum[2] + ssum[3];
    const float q_all = ssq[0] + ssq[1] + ssq[2] + ssq[3];
    const float mean = s_all * (1.f / HID);
    const float var  = q_all * (1.f / HID) - mean * mean;
    const float rstd = rsqrtf(var + 1e-5f);
    unsigned short* orow = out + (size_t)row * HID;
#pragma unroll
    for (int i = 0; i < 4; i++) {
        float4 wv = ((const float4*)w)[t + (i << 8)];
        float4 bv = ((const float4*)bch)[t + (i << 8)];
        ushort4 o;
        o.x = f2bf((v[i].x - mean) * rstd * wv.x + bv.x);
        o.y = f2bf((v[i].y - mean) * rstd * wv.y + bv.y);
        o.z = f2bf((v[i].z - mean) * rstd * wv.z + bv.z);
        o.w = f2bf((v[i].w - mean) * rstd * wv.w + bv.w);
        ((ushort4*)orow)[t + (i << 8)] = o;
    }
}

// ------------- transpose + fp32->bf16: W[K][N] -> Wt[N][K] ----------------------
__global__ __launch_bounds__(256) void transconv(const float* __restrict__ W,
        unsigned short* __restrict__ Wt, int K, int N) {
    __shared__ float tileT[128 * 65];   // [n][k], pad 65 (33.3 KB)
    const int n0 = blockIdx.x << 7, k0 = blockIdx.y << 6;
    const int t = threadIdx.x;
#pragma unroll
    for (int it = 0; it < 8; it++) {
        int idx = (it << 8) + t;
        int r = idx >> 5;            // k row 0..63
        int c4 = idx & 31;           // float4 column 0..31
        float4 v = *(const float4*)(W + (size_t)(k0 + r) * N + n0 + (c4 << 2));
        tileT[((c4 << 2) + 0) * 65 + r] = v.x;
        tileT[((c4 << 2) + 1) * 65 + r] = v.y;
        tileT[((c4 << 2) + 2) * 65 + r] = v.z;
        tileT[((c4 << 2) + 3) * 65 + r] = v.w;
    }
    __syncthreads();
#pragma unroll
    for (int it = 0; it < 4; it++) {
        int idx = (it << 8) + t;
        int n = idx >> 3;            // 0..127
        int k8 = idx & 7;            // ushort8 column, 0..7 (8 k each)
        const float* src = &tileT[n * 65 + (k8 << 3)];
        us8 o;
#pragma unroll
        for (int e = 0; e < 8; e++) o[e] = f2bf(src[e]);
        *(us8*)(Wt + (size_t)(n0 + n) * K + k0 + (k8 << 3)) = o;
    }
}

// =================================================================================
// 256x256 pipelined GEMM core (m201 geometry). 512 threads = 8 waves (2M x 4N),
// per-wave output 128x64. BK=64 as two K=32 halves. K hardcoded 4096 (64 tiles).
//
// LDS: 2 buffers x { A-ks0, A-ks1, B-ks0, B-ks1 } each [256][32] bf16 = 128 KB.
// 4 phases per K-tile:
//   ph1 (ks0, i=0..3): 8 ds_read (4A+4B) | stage A-ks0(t+1) | bar; lgkm0; 16 MFMA; bar
//   ph2 (ks0, i=4..7): 4 ds_read (A; B regs reused) | stage B-ks0(t+1) | ... ; vmcnt(4); bar
//   ph3 (ks1, i=0..3): 8 ds_read | stage A-ks1(t+1) | ...
//   ph4 (ks1, i=4..7): 4 ds_read | stage B-ks1(t+1) | ... ; vmcnt(4); bar
// Per wave: exactly 2 global_load_lds per phase -> vmcnt(4) leaves the 2 newest
// half-stages (just issued) in flight and forces the sub-tiles needed 1 phase
// later; every staged sub-tile has >= 4 phases (~1000 cyc) of slack.
//
// Swizzle (both-sides): LDS linear for global_load_lds; global source column
// pre-permuted with q = (lane&3)^((lane>>3)&3) (wave/issue-independent), ds_read
// applies chunk ^ ((row>>1)&3) -> 2 lanes/bank pair = conflict-free.
// =================================================================================

#define T256_PHASE(CB, KS, IH, READ_B, STAGE_CALL, DO_VM)                         \
  {                                                                               \
    _Pragma("unroll") for (int ii = 0; ii < 4; ii++)                              \
        af[ii] = ldA(CB, KS, ((IH) << 2) + ii);                                   \
    if (READ_B) {                                                                 \
      _Pragma("unroll") for (int jj = 0; jj < 4; jj++) bfv[jj] = ldB(CB, KS, jj); \
    }                                                                             \
    STAGE_CALL;                                                                   \
    __builtin_amdgcn_s_barrier();                                                 \
    asm volatile("s_waitcnt lgkmcnt(0)" ::: "memory");                            \
    __builtin_amdgcn_sched_barrier(0);                                            \
    __builtin_amdgcn_s_setprio(1);                                                \
    _Pragma("unroll") for (int ii = 0; ii < 4; ii++)                              \
      _Pragma("unroll") for (int jj = 0; jj < 4; jj++)                            \
        acc[((IH) << 2) + ii][jj] = __builtin_amdgcn_mfma_f32_16x16x32_bf16(      \
            af[ii], bfv[jj], acc[((IH) << 2) + ii][jj], 0, 0, 0);                 \
    __builtin_amdgcn_s_setprio(0);                                                \
    if (DO_VM) asm volatile("s_waitcnt vmcnt(4)" ::: "memory");                   \
    __builtin_amdgcn_s_barrier();                                                 \
  }

#define T256_TILE(TT, CB, PT)                                                     \
  {                                                                               \
    bf16x8 af[4], bfv[4];                                                         \
    T256_PHASE(CB, 0, 0, 1, stage(GA, (((CB)^1) << 15)        , (PT), 0), 0)      \
    T256_PHASE(CB, 0, 1, 0, stage(GB, (((CB)^1) << 15) + 16384, (PT), 0), 1)      \
    T256_PHASE(CB, 1, 0, 1, stage(GA, (((CB)^1) << 15) +  8192, (PT), 1), 0)      \
    T256_PHASE(CB, 1, 1, 0, stage(GB, (((CB)^1) << 15) + 24576, (PT), 1), 1)      \
  }

__device__ __forceinline__ void gemm_core_256(
        const unsigned short* __restrict__ GA,   // A panel base (bm*256 rows), [.][4096]
        const unsigned short* __restrict__ GB,   // B panel base (bn*256 rows), [.][4096]
        unsigned short* lds,                     // 65536 ushorts (128 KB)
        f32x4 acc[8][4]) {
    const int t = threadIdx.x;
    const int wave = t >> 6, lane = t & 63, quad = lane >> 4, l16 = lane & 15;
    const int waveM = wave >> 2, waveN = wave & 3;
    const int sq8 = (((lane & 3) ^ ((lane >> 3) & 3)) << 3);  // pre-swizzled src col

    // stage one [256][32] sub-tile: 2 x global_load_lds per thread (1KB per wave-issue)
    auto stage = [&](const unsigned short* G, int ldsOff, int tau, int ks) {
#pragma unroll
        for (int u = 0; u < 2; u++) {
            const int grp = (u << 3) + wave;          // 16-row group, 0..15
            const int r = (grp << 4) + (lane >> 2);   // row 0..255
            gld16(G + ((size_t)r << 12) + (tau << 6) + (ks << 5) + sq8,
                  lds + ldsOff + (grp << 9));
        }
    };
    auto ldA = [&](int buf, int ks, int i) -> bf16x8 {
        const int r = (waveM << 7) + (i << 4) + l16;  // 0..255
        return ((const bf16x8*)(lds + (buf << 15) + (ks << 13)))
            [(r << 2) + (quad ^ ((r >> 1) & 3))];
    };
    auto ldB = [&](int buf, int ks, int j) -> bf16x8 {
        const int r = (waveN << 6) + (j << 4) + l16;  // 0..255
        return ((const bf16x8*)(lds + (buf << 15) + 16384 + (ks << 13)))
            [(r << 2) + (quad ^ ((r >> 1) & 3))];
    };

    // prologue: tile0 -> buf0 (8 vm-ops); force A-ks0,B-ks0 (oldest 4) complete.
    stage(GA, 0,     0, 0);
    stage(GB, 16384, 0, 0);
    stage(GA, 8192,  0, 1);
    stage(GB, 24576, 0, 1);
    asm volatile("s_waitcnt vmcnt(4)" ::: "memory");
    __builtin_amdgcn_s_barrier();

    for (int tt = 0; tt < 64; tt += 2) {
        T256_TILE(tt,     0, tt + 1)
        T256_TILE(tt + 1, 1, (tt == 62) ? 63 : tt + 2)   // tail: dummy re-stage of 63
    }
    asm volatile("s_waitcnt vmcnt(0)" ::: "memory");      // drain dangling prefetches
}

// ---------------- QKV GEMM: A[2048][4096] x Bt[12288][4096] + bias, scatter -----
// Grid 384 = 8 bm x 48 bn. bm = blockIdx&7 -> each XCD pins ONE 2MB A-panel in
// its L2 for the whole kernel; B panels stream through L3.
__global__ __launch_bounds__(512, 2) void gemm_qkv16(
        const unsigned short* __restrict__ A,
        const unsigned short* __restrict__ Bt,
        const float* __restrict__ bias,
        unsigned short* __restrict__ qb,
        unsigned short* __restrict__ kb,
        unsigned short* __restrict__ vt) {
    __shared__ unsigned short lds[65536];
    const int orig = blockIdx.x;
    const int bm = orig & 7, bn = orig >> 3;
    const int t = threadIdx.x;
    const int wave = t >> 6, lane = t & 63, quad = lane >> 4, l16 = lane & 15;
    const int waveM = wave >> 2, waveN = wave & 3;

    const f32x4 fz = {0.f, 0.f, 0.f, 0.f};
    f32x4 acc[8][4];
#pragma unroll
    for (int i = 0; i < 8; i++)
#pragma unroll
        for (int j = 0; j < 4; j++) acc[i][j] = fz;

    gemm_core_256(A + ((size_t)bm << 20), Bt + ((size_t)bn << 20), lds, acc);

    const int nbase = (bn << 8) + (waveN << 6);
    const int which = nbase >> 12;           // 0=q 1=k 2=v (block-uniform: 4096%256==0)
#pragma unroll
    for (int ii = 0; ii < 8; ii++) {
#pragma unroll
        for (int jj = 0; jj < 4; jj++) {
#pragma unroll
            for (int r = 0; r < 4; r++) {
                int m = (bm << 8) + (waveM << 7) + (ii << 4) + (quad << 2) + r;
                int n = nbase + (jj << 4) + l16;
                float v = acc[ii][jj][r] + bias[n];
                unsigned short bvv = f2bf(v);
                int bb = m >> 10, s = m & 1023;
                int h = n & 4095, head = h >> 7, hd = h & 127;
                size_t bh = (size_t)(bb << 5) + head;
                if (which == 0)      qb[(bh * S_LEN + s) * HDIM + hd] = bvv;
                else if (which == 1) kb[(bh * S_LEN + s) * HDIM + hd] = bvv;
                else                 vt[(bh * HDIM + hd) * S_LEN + s] = bvv;
            }
        }
    }
}

// =================================================================================
// 128x256 pipelined core (round-1 structure) — kept for proj (exact 256-block fit).
// =================================================================================

#define GEMM_PHASE(CB, KS, PFT, PFB, DO_VM)                                       \
  {                                                                               \
    bf16x8 af[4], bfv[4];                                                         \
    _Pragma("unroll") for (int ii = 0; ii < 4; ii++) af[ii] = ldA(CB, KS, ii);    \
    _Pragma("unroll") for (int jj = 0; jj < 4; jj++) bfv[jj] = ldB(CB, KS, jj);   \
    stageA(PFT, KS, PFB);                                                         \
    stageB(PFT, KS, PFB);                                                         \
    __builtin_amdgcn_s_barrier();                                                 \
    asm volatile("s_waitcnt lgkmcnt(0)" ::: "memory");                            \
    __builtin_amdgcn_sched_barrier(0);                                            \
    __builtin_amdgcn_s_setprio(1);                                                \
    _Pragma("unroll") for (int ii = 0; ii < 4; ii++)                              \
      _Pragma("unroll") for (int jj = 0; jj < 4; jj++)                            \
        acc[ii][jj] = __builtin_amdgcn_mfma_f32_16x16x32_bf16(                    \
            af[ii], bfv[jj], acc[ii][jj], 0, 0, 0);                               \
    __builtin_amdgcn_s_setprio(0);                                                \
    if (DO_VM) asm volatile("s_waitcnt vmcnt(6)" ::: "memory");                   \
    __builtin_amdgcn_s_barrier();                                                 \
  }

#define GEMM_TILE(TT, CB)                                                         \
  {                                                                               \
    int pf_ = (TT) + 2; if (pf_ > 63) pf_ = 63;                                   \
    GEMM_PHASE(CB, 0, pf_, ((CB) + 2) % 3, 0)                                     \
    GEMM_PHASE(CB, 1, pf_, ((CB) + 2) % 3, 1)                                     \
  }

__device__ __forceinline__ void gemm_core_8w(
        const unsigned short* __restrict__ GA,   // A panel base row (bm*128), [.][4096]
        const unsigned short* __restrict__ GB,   // B panel base row (bn*256), [.][4096]
        unsigned short* lds,                     // 73728 ushorts (144 KB)
        f32x4 acc[4][4]) {
    const int t = threadIdx.x;
    const int wave = t >> 6, lane = t & 63, quad = lane >> 4, l16 = lane & 15;
    const int waveM = wave >> 2, waveN = wave & 3;
    const int srow = lane >> 2;                               // 0..15 in 16-row group
    const int scol = (((lane & 3) ^ ((lane >> 3) & 3)) << 3); // pre-swizzled src col

    auto stageA = [&](int tau, int ks, int buf) {
        const int row = (wave << 4) + srow;                   // 0..127
        gld16(GA + ((size_t)row << 12) + (tau << 6) + (ks << 5) + scol,
              lds + buf * 24576 + (ks << 12) + (wave << 9));
    };
    auto stageB = [&](int tau, int ks, int buf) {
#pragma unroll
        for (int u = 0; u < 2; u++) {
            const int ii = (wave << 1) + u;
            const int row = (ii << 4) + srow;                 // 0..255
            gld16(GB + ((size_t)row << 12) + (tau << 6) + (ks << 5) + scol,
                  lds + buf * 24576 + 8192 + (ks << 13) + (ii << 9));
        }
    };
    auto ldA = [&](int buf, int ks, int ii) -> bf16x8 {
        const int r = (waveM << 6) + (ii << 4) + l16;         // 0..127
        return ((const bf16x8*)(lds + buf * 24576 + (ks << 12)))
            [(r << 2) + (quad ^ ((r >> 1) & 3))];
    };
    auto ldB = [&](int buf, int ks, int jj) -> bf16x8 {
        const int r = (waveN << 6) + (jj << 4) + l16;         // 0..255
        return ((const bf16x8*)(lds + buf * 24576 + 8192 + (ks << 13)))
            [(r << 2) + (quad ^ ((r >> 1) & 3))];
    };

    stageA(0, 0, 0); stageB(0, 0, 0); stageA(0, 1, 0); stageB(0, 1, 0);
    stageA(1, 0, 1); stageB(1, 0, 1); stageA(1, 1, 1); stageB(1, 1, 1);
    asm volatile("s_waitcnt vmcnt(6)" ::: "memory");
    __builtin_amdgcn_s_barrier();

    for (int tb = 0; tb < 63; tb += 3) {
        GEMM_TILE(tb,     0)
        GEMM_TILE(tb + 1, 1)
        GEMM_TILE(tb + 2, 2)
    }
    GEMM_TILE(63, 0)
    asm volatile("s_waitcnt vmcnt(0)" ::: "memory");
}

// ---------------- proj GEMM: ctx[2048][4096] x ow_t[4096][4096] -> fp32 out ------
// Grid 256 = 16 x 16 = exactly 1 round of 256 CUs.
__global__ __launch_bounds__(512, 2) void gemm_proj8(
        const unsigned short* __restrict__ A,
        const unsigned short* __restrict__ Bt,
        float* __restrict__ outf) {
    __shared__ unsigned short lds[73728];
    const int orig = blockIdx.x;
    const int wg = ((orig & 7) * 32) + (orig >> 3);
    const int bm = wg >> 4, bn = wg & 15;
    const int t = threadIdx.x;
    const int wave = t >> 6, lane = t & 63, quad = lane >> 4, l16 = lane & 15;
    const int waveM = wave >> 2, waveN = wave & 3;

    const f32x4 fz = {0.f, 0.f, 0.f, 0.f};
    f32x4 acc[4][4];
#pragma unroll
    for (int i = 0; i < 4; i++)
#pragma unroll
        for (int j = 0; j < 4; j++) acc[i][j] = fz;

    gemm_core_8w(A + ((size_t)bm << 19), Bt + ((size_t)bn << 20), lds, acc);

#pragma unroll
    for (int ii = 0; ii < 4; ii++)
#pragma unroll
        for (int jj = 0; jj < 4; jj++)
#pragma unroll
            for (int r = 0; r < 4; r++) {
                int m = (bm << 7) + (waveM << 6) + (ii << 4) + (quad << 2) + r;
                int n = (bn << 8) + (waveN << 6) + (jj << 4) + l16;
                outf[((size_t)m << 12) + n] = acc[ii][jj][r];
            }
}

// ---------------- flash attention: 64-query tile per block, causal ---------------
__global__ __launch_bounds__(256) void attn_kernel(
        const unsigned short* __restrict__ qbuf,   // [64][1024][128]
        const unsigned short* __restrict__ kbuf,   // [64][1024][128]
        const unsigned short* __restrict__ vtbuf,  // [64][128][1024]
        const float* __restrict__ mask,            // [2][1024]
        unsigned short* __restrict__ ctx) {        // [2048][4096]
    __shared__ unsigned short q_lds[64 * 128];
    __shared__ unsigned short k_lds[64 * 128];
    __shared__ unsigned short v_lds[128 * 64];     // [hd][key]
    __shared__ unsigned short p_lds[64 * 64];
    const int t = threadIdx.x;
    const int wave = t >> 6, lane = t & 63, quad = lane >> 4, l16 = lane & 15;
    const int bq = blockIdx.x, bh = blockIdx.y;
    const int q0 = bq << 6;
    const int b = bh >> 5;
    const unsigned short* Q  = qbuf  + (size_t)bh * S_LEN * HDIM;
    const unsigned short* Kp = kbuf  + (size_t)bh * S_LEN * HDIM;
    const unsigned short* Vp = vtbuf + (size_t)bh * HDIM * S_LEN;

    {
        int r = t >> 4, c = (t & 15) << 3;
#pragma unroll
        for (int it = 0; it < 4; it++)
            gld16(Q + (size_t)(q0 + r + (it << 4)) * HDIM + c,
                  q_lds + ((((it << 8) + (wave << 6))) << 3));
    }

    const f32x4 fz = {0.f, 0.f, 0.f, 0.f};
    f32x4 o[8];
#pragma unroll
    for (int n = 0; n < 8; n++) o[n] = fz;
    float l_i[4] = {0.f, 0.f, 0.f, 0.f};
    const float scale = 0.08838834764831845f;   // 1/sqrt(128)
    const float* mrow = mask + b * S_LEN;

    for (int kt = 0; kt <= bq; kt++) {
        const int k0 = kt << 6;
        {
            int rk = t >> 4, ck = (t & 15) << 3;
            int rv = t >> 3, cv = (t & 7) << 3;
#pragma unroll
            for (int it = 0; it < 4; it++) {
                gld16(Kp + (size_t)(k0 + rk + (it << 4)) * HDIM + ck,
                      k_lds + (((it << 8) + (wave << 6)) << 3));
                gld16(Vp + (size_t)(rv + (it << 5)) * S_LEN + k0 + cv,
                      v_lds + (((it << 8) + (wave << 6)) << 3));
            }
        }
        __syncthreads();

        f32x4 sacc[4];
#pragma unroll
        for (int j = 0; j < 4; j++) sacc[j] = fz;
        const bf16x8* qv = (const bf16x8*)q_lds;
        const bf16x8* kv = (const bf16x8*)k_lds;
#pragma unroll
        for (int kk = 0; kk < 4; kk++) {
            bf16x8 aq = qv[(((wave << 4) + l16) << 4) + (kk << 2) + quad];
#pragma unroll
            for (int j = 0; j < 4; j++) {
                bf16x8 bk = kv[((((j << 4) + l16)) << 4) + (kk << 2) + quad];
                sacc[j] = __builtin_amdgcn_mfma_f32_16x16x32_bf16(aq, bk, sacc[j], 0, 0, 0);
            }
        }

#pragma unroll
        for (int r = 0; r < 4; r++) {
            int qrow = q0 + (wave << 4) + (quad << 2) + r;
#pragma unroll
            for (int j = 0; j < 4; j++) {
                int key = k0 + (j << 4) + l16;
                float x = sacc[j][r] * scale + mrow[key];
                if (key > qrow) x -= 10000.0f;
                float p = __expf(x);
                l_i[r] += p;
                p_lds[((wave << 4) + (quad << 2) + r) * 64 + (j << 4) + l16] = f2bf(p);
            }
        }
        __syncthreads();

        const bf16x8* pvv = (const bf16x8*)p_lds;
        const bf16x8* vv = (const bf16x8*)v_lds;
#pragma unroll
        for (int ks = 0; ks < 2; ks++) {
            bf16x8 ap = pvv[(((wave << 4) + l16) << 3) + (ks << 2) + quad];
#pragma unroll
            for (int n = 0; n < 8; n++) {
                bf16x8 bvv = vv[((((n << 4) + l16)) << 3) + (ks << 2) + quad];
                o[n] = __builtin_amdgcn_mfma_f32_16x16x32_bf16(ap, bvv, o[n], 0, 0, 0);
            }
        }
        __syncthreads();
    }

#pragma unroll
    for (int r = 0; r < 4; r++) {
        float l = l_i[r];
#pragma unroll
        for (int off = 1; off < 16; off <<= 1) l += __shfl_xor(l, off);
        float inv = 1.0f / l;
        int qrow = q0 + (wave << 4) + (quad << 2) + r;
        size_t base = ((size_t)(b * S_LEN + qrow)) * HID + ((size_t)(bh & 31) << 7);
#pragma unroll
        for (int n = 0; n < 8; n++)
            ctx[base + (n << 4) + l16] = f2bf(o[n][r] * inv);
    }
}

extern "C" void kernel_launch(void* const* d_in, const int* in_sizes, int n_in,
                              void* d_out, int out_size, void* d_ws, size_t ws_size,
                              hipStream_t stream) {
    const float* x       = (const float*)d_in[0];
    const float* mask    = (const float*)d_in[1];
    const float* norm_w  = (const float*)d_in[2];
    const float* norm_b  = (const float*)d_in[3];
    const float* qkv_w   = (const float*)d_in[4];
    const float* qkv_b   = (const float*)d_in[5];
    const float* attn_ow = (const float*)d_in[6];
    float* out = (float*)d_out;

    char* ws = (char*)d_ws;
    size_t off = 0;
    auto alloc = [&](size_t bytes) {
        char* p = ws + off;
        off += (bytes + 255) & ~(size_t)255;
        return p;
    };
    unsigned short* inp_norm = (unsigned short*)alloc((size_t)2048 * HID * 2);
    unsigned short* qkv_wt   = (unsigned short*)alloc((size_t)3 * HID * HID * 2);
    unsigned short* ow_t     = (unsigned short*)alloc((size_t)HID * HID * 2);
    unsigned short* qb       = (unsigned short*)alloc((size_t)64 * S_LEN * HDIM * 2);
    unsigned short* kb       = (unsigned short*)alloc((size_t)64 * S_LEN * HDIM * 2);
    unsigned short* vt       = (unsigned short*)alloc((size_t)64 * S_LEN * HDIM * 2);
    unsigned short* ctx      = (unsigned short*)alloc((size_t)2048 * HID * 2);

    ln_kernel<<<2048, 256, 0, stream>>>(x, norm_w, norm_b, inp_norm);
    transconv<<<dim3(3 * HID / 128, HID / 64), 256, 0, stream>>>(qkv_w, qkv_wt, HID, 3 * HID);
    transconv<<<dim3(HID / 128, HID / 64), 256, 0, stream>>>(attn_ow, ow_t, HID, HID);
    gemm_qkv16<<<384, 512, 0, stream>>>(inp_norm, qkv_wt, qkv_b, qb, kb, vt);
    attn_kernel<<<dim3(16, 64), 256, 0, stream>>>(qb, kb, vt, mask, ctx);
    gemm_proj8<<<256, 512, 0, stream>>>(ctx, ow_t, out);
}

// Round 3
// 771.638 us; speedup vs baseline: 1.1389x; 1.0504x over previous
//
#include <hip/hip_runtime.h>
#include <stdint.h>

// DeepSpeed self-attention forward, bf16-MFMA implementation.
// B=2, S=1024, H=4096, NH=32, HD=128. All matmuls via mfma_f32_16x16x32_bf16.
// Round 6: QKV = 256x192 tile, 512 blocks (2 exact rounds), 3-phase staging
// slack, vmcnt(5)/vmcnt(2) counted waits. Proj = 128x256 core with staging
// moved to ph1 (3-phase slack on its vmcnt(6)).

#define S_LEN 1024
#define HID   4096
#define NHEAD 32
#define HDIM  128

typedef __attribute__((ext_vector_type(8))) short bf16x8;   // 8 bf16 (4 VGPRs)
typedef __attribute__((ext_vector_type(4))) float f32x4;    // MFMA C/D
typedef __attribute__((ext_vector_type(8))) unsigned short us8; // 16B store

__device__ __forceinline__ unsigned short f2bf(float f) {
    union { float f; unsigned u; } v; v.f = f;
    unsigned r = v.u + 0x7fffu + ((v.u >> 16) & 1u);
    return (unsigned short)(r >> 16);
}

__device__ __forceinline__ void gld16(const unsigned short* g, unsigned short* l) {
    __builtin_amdgcn_global_load_lds(
        (const __attribute__((address_space(1))) void*)g,
        (__attribute__((address_space(3))) void*)l, 16, 0, 0);
}

// ---------------- LayerNorm + bf16 cast: x[2048][4096] -> inp_norm bf16 ----------
__global__ __launch_bounds__(256) void ln_kernel(const float* __restrict__ x,
        const float* __restrict__ w, const float* __restrict__ bch,
        unsigned short* __restrict__ out) {
    const int row = blockIdx.x;
    const int t = threadIdx.x;
    const float* xr = x + (size_t)row * HID;
    float4 v[4];
    float sum = 0.f, sq = 0.f;
#pragma unroll
    for (int i = 0; i < 4; i++) {
        v[i] = ((const float4*)xr)[t + (i << 8)];
        sum += v[i].x + v[i].y + v[i].z + v[i].w;
        sq  += v[i].x*v[i].x + v[i].y*v[i].y + v[i].z*v[i].z + v[i].w*v[i].w;
    }
#pragma unroll
    for (int off = 32; off; off >>= 1) {
        sum += __shfl_down(sum, off);
        sq  += __shfl_down(sq, off);
    }
    __shared__ float ssum[4], ssq[4];
    if ((t & 63) == 0) { ssum[t >> 6] = sum; ssq[t >> 6] = sq; }
    __syncthreads();
    const float s_all = ssum[0] + ssum[1] + ssum[2] + ssum[3];
    const float q_all = ssq[0] + ssq[1] + ssq[2] + ssq[3];
    const float mean = s_all * (1.f / HID);
    const float var  = q_all * (1.f / HID) - mean * mean;
    const float rstd = rsqrtf(var + 1e-5f);
    unsigned short* orow = out + (size_t)row * HID;
#pragma unroll
    for (int i = 0; i < 4; i++) {
        float4 wv = ((const float4*)w)[t + (i << 8)];
        float4 bv = ((const float4*)bch)[t + (i << 8)];
        ushort4 o;
        o.x = f2bf((v[i].x - mean) * rstd * wv.x + bv.x);
        o.y = f2bf((v[i].y - mean) * rstd * wv.y + bv.y);
        o.z = f2bf((v[i].z - mean) * rstd * wv.z + bv.z);
        o.w = f2bf((v[i].w - mean) * rstd * wv.w + bv.w);
        ((ushort4*)orow)[t + (i << 8)] = o;
    }
}

// ------------- transpose + fp32->bf16: W[K][N] -> Wt[N][K] ----------------------
__global__ __launch_bounds__(256) void transconv(const float* __restrict__ W,
        unsigned short* __restrict__ Wt, int K, int N) {
    __shared__ float tileT[128 * 65];   // [n][k], pad 65 (33.3 KB)
    const int n0 = blockIdx.x << 7, k0 = blockIdx.y << 6;
    const int t = threadIdx.x;
#pragma unroll
    for (int it = 0; it < 8; it++) {
        int idx = (it << 8) + t;
        int r = idx >> 5;            // k row 0..63
        int c4 = idx & 31;           // float4 column 0..31
        float4 v = *(const float4*)(W + (size_t)(k0 + r) * N + n0 + (c4 << 2));
        tileT[((c4 << 2) + 0) * 65 + r] = v.x;
        tileT[((c4 << 2) + 1) * 65 + r] = v.y;
        tileT[((c4 << 2) + 2) * 65 + r] = v.z;
        tileT[((c4 << 2) + 3) * 65 + r] = v.w;
    }
    __syncthreads();
#pragma unroll
    for (int it = 0; it < 4; it++) {
        int idx = (it << 8) + t;
        int n = idx >> 3;            // 0..127
        int k8 = idx & 7;            // ushort8 column, 0..7 (8 k each)
        const float* src = &tileT[n * 65 + (k8 << 3)];
        us8 o;
#pragma unroll
        for (int e = 0; e < 8; e++) o[e] = f2bf(src[e]);
        *(us8*)(Wt + (size_t)(n0 + n) * K + k0 + (k8 << 3)) = o;
    }
}

// =================================================================================
// QKV GEMM core: 256x192 tile, 512 threads = 8 waves (2M x 4N), per-wave 128x48.
// BK=64 (2 K=32 halves). K=4096 (64 tiles). LDS 2 x 56 KB = 112 KB:
//   buf: A-ks0 [256][32] (16KB) | A-ks1 [256][32] (16KB) | B [192][64] (24KB)
// 4 phases/tile, 12 MFMA each. Staging (per-thread vm ops):
//   ph1: stage A-ks0(t+1) [2] + B(t+1) [3]    (3-phase slack to their wait)
//   ph2: --            ; vmcnt(5)  (forces A-ks1(t), issued ph3(t-1), 3 ph old)
//   ph3: stage A-ks1(t+1) [2]
//   ph4: --            ; vmcnt(2)  (forces A-ks0(t+1)+B(t+1), issued ph1, 3 ph old)
// Swizzles (both-sides, LDS linear for global_load_lds):
//   A (4x16B chunks/row):  lds chunk c holds global chunk c ^ ((row>>1)&3)
//   B (8x16B chunks/row):  lds chunk c holds global chunk c ^ (row&7)
// Both give 2 lanes/bank-group on fragment ds_read_b128 = conflict-free.
// =================================================================================

#define Q_PHASE(CB, KS, IH, READB, STAGE, VMSTMT)                                 \
  {                                                                               \
    _Pragma("unroll") for (int ii = 0; ii < 4; ii++)                              \
        af[ii] = ldA(CB, KS, ((IH) << 2) + ii);                                   \
    if (READB) {                                                                  \
      _Pragma("unroll") for (int jj = 0; jj < 3; jj++) bfv[jj] = ldB(CB, KS, jj); \
    }                                                                             \
    STAGE;                                                                        \
    __builtin_amdgcn_s_barrier();                                                 \
    asm volatile("s_waitcnt lgkmcnt(0)" ::: "memory");                            \
    __builtin_amdgcn_sched_barrier(0);                                            \
    __builtin_amdgcn_s_setprio(1);                                                \
    _Pragma("unroll") for (int ii = 0; ii < 4; ii++)                              \
      _Pragma("unroll") for (int jj = 0; jj < 3; jj++)                            \
        acc[((IH) << 2) + ii][jj] = __builtin_amdgcn_mfma_f32_16x16x32_bf16(      \
            af[ii], bfv[jj], acc[((IH) << 2) + ii][jj], 0, 0, 0);                 \
    __builtin_amdgcn_s_setprio(0);                                                \
    VMSTMT;                                                                       \
    __builtin_amdgcn_s_barrier();                                                 \
  }

#define Q_TILE(TT, CB)                                                            \
  {                                                                               \
    bf16x8 af[4], bfv[3];                                                         \
    int pf_ = (TT) + 1; if (pf_ > 63) pf_ = 63;                                   \
    Q_PHASE(CB, 0, 0, 1, { stgA(pf_, 0, (CB)^1); stgB(pf_, (CB)^1); }, ((void)0)) \
    Q_PHASE(CB, 0, 1, 0, ((void)0), asm volatile("s_waitcnt vmcnt(5)":::"memory"))\
    Q_PHASE(CB, 1, 0, 1, { stgA(pf_, 1, (CB)^1); }, ((void)0))                    \
    Q_PHASE(CB, 1, 1, 0, ((void)0), asm volatile("s_waitcnt vmcnt(2)":::"memory"))\
  }

// Grid 512 = 8 bm x 64 bn = exactly 2 rounds of 256 CUs. bm = orig&7 pins one
// 2MB A-panel per XCD L2; B (1.5MB/panel) streams via L3.
__global__ __launch_bounds__(512, 2) void gemm_qkv192(
        const unsigned short* __restrict__ A,
        const unsigned short* __restrict__ Bt,
        const float* __restrict__ bias,
        unsigned short* __restrict__ qb,
        unsigned short* __restrict__ kb,
        unsigned short* __restrict__ vt) {
    __shared__ unsigned short lds[57344];   // 112 KB
    const int orig = blockIdx.x;
    const int bm = orig & 7, bn = orig >> 3;      // bn 0..63
    const int t = threadIdx.x;
    const int wave = t >> 6, lane = t & 63, quad = lane >> 4, l16 = lane & 15;
    const int waveM = wave >> 2, waveN = wave & 3;

    const unsigned short* GA = A  + ((size_t)bm << 8) * HID;          // 256 rows
    const unsigned short* GB = Bt + ((size_t)bn * 192) * HID;         // 192 rows

    const int sqa = (((lane & 3) ^ ((lane >> 3) & 3)) << 3);  // A src col (el)
    const int sqb = (((lane & 7) ^ ((lane >> 3) & 7)) << 3);  // B src col (el)

    // A sub-tile ks: [256][32] at buf*28672 + ks*8192. 2 granules/wave (16 rows, 1KB).
    auto stgA = [&](int tau, int ks, int buf) {
#pragma unroll
        for (int u = 0; u < 2; u++) {
            const int g = (u << 3) + wave;                // 0..15
            const int row = (g << 4) + (lane >> 2);       // 0..255
            gld16(GA + (size_t)row * HID + (tau << 6) + (ks << 5) + sqa,
                  lds + buf * 28672 + (ks << 13) + (g << 9));
        }
    };
    // B tile: [192][64] at buf*28672 + 16384. 3 granules/wave (8 rows, 1KB).
    auto stgB = [&](int tau, int buf) {
#pragma unroll
        for (int u = 0; u < 3; u++) {
            const int g = (u << 3) + wave;                // 0..23
            const int row = (g << 3) + (lane >> 3);       // 0..191
            gld16(GB + (size_t)row * HID + (tau << 6) + sqb,
                  lds + buf * 28672 + 16384 + (g << 9));
        }
    };
    auto ldA = [&](int buf, int ks, int i) -> bf16x8 {
        const int r = (waveM << 7) + (i << 4) + l16;      // 0..255
        return ((const bf16x8*)lds)
            [((buf * 28672 + (ks << 13)) >> 3) + (r << 2) + (quad ^ ((r >> 1) & 3))];
    };
    auto ldB = [&](int buf, int ks, int j) -> bf16x8 {
        const int r = waveN * 48 + (j << 4) + l16;        // 0..191
        return ((const bf16x8*)lds)
            [((buf * 28672 + 16384) >> 3) + (r << 3) + (((ks << 2) | quad) ^ (r & 7))];
    };

    const f32x4 fz = {0.f, 0.f, 0.f, 0.f};
    f32x4 acc[8][3];
#pragma unroll
    for (int i = 0; i < 8; i++)
#pragma unroll
        for (int j = 0; j < 3; j++) acc[i][j] = fz;

    // prologue: tile0 -> buf0 (7 vm-ops); force A-ks0(0)+B(0) (oldest 5).
    stgA(0, 0, 0);
    stgB(0, 0);
    stgA(0, 1, 0);
    asm volatile("s_waitcnt vmcnt(2)" ::: "memory");
    __builtin_amdgcn_s_barrier();

    for (int tt = 0; tt < 64; tt += 2) {
        Q_TILE(tt,     0)
        Q_TILE(tt + 1, 1)
    }
    asm volatile("s_waitcnt vmcnt(0)" ::: "memory");      // drain dummies

    // epilogue: scatter with bias. n-range of a j-frag never crosses a 16-align
    // boundary, so q/k/v selection is uniform within it (4096 % 16 == 0).
#pragma unroll
    for (int ii = 0; ii < 8; ii++) {
#pragma unroll
        for (int jj = 0; jj < 3; jj++) {
#pragma unroll
            for (int r = 0; r < 4; r++) {
                int m = (bm << 8) + (waveM << 7) + (ii << 4) + (quad << 2) + r;
                int n = bn * 192 + waveN * 48 + (jj << 4) + l16;
                float v = acc[ii][jj][r] + bias[n];
                unsigned short bvv = f2bf(v);
                int bb = m >> 10, s = m & 1023;
                int which = n >> 12;           // 0=q 1=k 2=v
                int h = n & 4095, head = h >> 7, hd = h & 127;
                size_t bh = (size_t)(bb << 5) + head;
                if (which == 0)      qb[(bh * S_LEN + s) * HDIM + hd] = bvv;
                else if (which == 1) kb[(bh * S_LEN + s) * HDIM + hd] = bvv;
                else                 vt[(bh * HDIM + hd) * S_LEN + s] = bvv;
            }
        }
    }
}

// =================================================================================
// 128x256 pipelined core — proj. Staging for tile t+2 all issued in ph1 (6 ops);
// vmcnt(6) at ph2-end forces tile t+1's loads (issued ph1(t-1), 3 phases old).
// =================================================================================

#define GEMM_PHASE(CB, KS, STAGE, VMSTMT)                                         \
  {                                                                               \
    bf16x8 af[4], bfv[4];                                                         \
    _Pragma("unroll") for (int ii = 0; ii < 4; ii++) af[ii] = ldA(CB, KS, ii);    \
    _Pragma("unroll") for (int jj = 0; jj < 4; jj++) bfv[jj] = ldB(CB, KS, jj);   \
    STAGE;                                                                        \
    __builtin_amdgcn_s_barrier();                                                 \
    asm volatile("s_waitcnt lgkmcnt(0)" ::: "memory");                            \
    __builtin_amdgcn_sched_barrier(0);                                            \
    __builtin_amdgcn_s_setprio(1);                                                \
    _Pragma("unroll") for (int ii = 0; ii < 4; ii++)                              \
      _Pragma("unroll") for (int jj = 0; jj < 4; jj++)                            \
        acc[ii][jj] = __builtin_amdgcn_mfma_f32_16x16x32_bf16(                    \
            af[ii], bfv[jj], acc[ii][jj], 0, 0, 0);                               \
    __builtin_amdgcn_s_setprio(0);                                                \
    VMSTMT;                                                                       \
    __builtin_amdgcn_s_barrier();                                                 \
  }

#define GEMM_TILE(TT, CB)                                                         \
  {                                                                               \
    int pf_ = (TT) + 2; if (pf_ > 63) pf_ = 63;                                   \
    const int pb_ = ((CB) + 2) % 3;                                               \
    GEMM_PHASE(CB, 0,                                                             \
        { stageA(pf_, 0, pb_); stageB(pf_, 0, pb_);                               \
          stageA(pf_, 1, pb_); stageB(pf_, 1, pb_); }, ((void)0))                 \
    GEMM_PHASE(CB, 1, ((void)0),                                                  \
        asm volatile("s_waitcnt vmcnt(6)" ::: "memory"))                          \
  }

__device__ __forceinline__ void gemm_core_8w(
        const unsigned short* __restrict__ GA,   // A panel base row (bm*128), [.][4096]
        const unsigned short* __restrict__ GB,   // B panel base row (bn*256), [.][4096]
        unsigned short* lds,                     // 73728 ushorts (144 KB)
        f32x4 acc[4][4]) {
    const int t = threadIdx.x;
    const int wave = t >> 6, lane = t & 63, quad = lane >> 4, l16 = lane & 15;
    const int waveM = wave >> 2, waveN = wave & 3;
    const int srow = lane >> 2;                               // 0..15 in 16-row group
    const int scol = (((lane & 3) ^ ((lane >> 3) & 3)) << 3); // pre-swizzled src col

    auto stageA = [&](int tau, int ks, int buf) {
        const int row = (wave << 4) + srow;                   // 0..127
        gld16(GA + ((size_t)row << 12) + (tau << 6) + (ks << 5) + scol,
              lds + buf * 24576 + (ks << 12) + (wave << 9));
    };
    auto stageB = [&](int tau, int ks, int buf) {
#pragma unroll
        for (int u = 0; u < 2; u++) {
            const int ii = (wave << 1) + u;
            const int row = (ii << 4) + srow;                 // 0..255
            gld16(GB + ((size_t)row << 12) + (tau << 6) + (ks << 5) + scol,
                  lds + buf * 24576 + 8192 + (ks << 13) + (ii << 9));
        }
    };
    auto ldA = [&](int buf, int ks, int ii) -> bf16x8 {
        const int r = (waveM << 6) + (ii << 4) + l16;         // 0..127
        return ((const bf16x8*)(lds + buf * 24576 + (ks << 12)))
            [(r << 2) + (quad ^ ((r >> 1) & 3))];
    };
    auto ldB = [&](int buf, int ks, int jj) -> bf16x8 {
        const int r = (waveN << 6) + (jj << 4) + l16;         // 0..255
        return ((const bf16x8*)(lds + buf * 24576 + 8192 + (ks << 13)))
            [(r << 2) + (quad ^ ((r >> 1) & 3))];
    };

    stageA(0, 0, 0); stageB(0, 0, 0); stageA(0, 1, 0); stageB(0, 1, 0);
    stageA(1, 0, 1); stageB(1, 0, 1); stageA(1, 1, 1); stageB(1, 1, 1);
    asm volatile("s_waitcnt vmcnt(6)" ::: "memory");
    __builtin_amdgcn_s_barrier();

    for (int tb = 0; tb < 63; tb += 3) {
        GEMM_TILE(tb,     0)
        GEMM_TILE(tb + 1, 1)
        GEMM_TILE(tb + 2, 2)
    }
    GEMM_TILE(63, 0)
    asm volatile("s_waitcnt vmcnt(0)" ::: "memory");
}

// ---------------- proj GEMM: ctx[2048][4096] x ow_t[4096][4096] -> fp32 out ------
// Grid 256 = 16 x 16 = exactly 1 round of 256 CUs.
__global__ __launch_bounds__(512, 2) void gemm_proj8(
        const unsigned short* __restrict__ A,
        const unsigned short* __restrict__ Bt,
        float* __restrict__ outf) {
    __shared__ unsigned short lds[73728];
    const int orig = blockIdx.x;
    const int wg = ((orig & 7) * 32) + (orig >> 3);
    const int bm = wg >> 4, bn = wg & 15;
    const int t = threadIdx.x;
    const int wave = t >> 6, lane = t & 63, quad = lane >> 4, l16 = lane & 15;
    const int waveM = wave >> 2, waveN = wave & 3;

    const f32x4 fz = {0.f, 0.f, 0.f, 0.f};
    f32x4 acc[4][4];
#pragma unroll
    for (int i = 0; i < 4; i++)
#pragma unroll
        for (int j = 0; j < 4; j++) acc[i][j] = fz;

    gemm_core_8w(A + ((size_t)bm << 19), Bt + ((size_t)bn << 20), lds, acc);

#pragma unroll
    for (int ii = 0; ii < 4; ii++)
#pragma unroll
        for (int jj = 0; jj < 4; jj++)
#pragma unroll
            for (int r = 0; r < 4; r++) {
                int m = (bm << 7) + (waveM << 6) + (ii << 4) + (quad << 2) + r;
                int n = (bn << 8) + (waveN << 6) + (jj << 4) + l16;
                outf[((size_t)m << 12) + n] = acc[ii][jj][r];
            }
}

// ---------------- flash attention: 64-query tile per block, causal ---------------
__global__ __launch_bounds__(256) void attn_kernel(
        const unsigned short* __restrict__ qbuf,   // [64][1024][128]
        const unsigned short* __restrict__ kbuf,   // [64][1024][128]
        const unsigned short* __restrict__ vtbuf,  // [64][128][1024]
        const float* __restrict__ mask,            // [2][1024]
        unsigned short* __restrict__ ctx) {        // [2048][4096]
    __shared__ unsigned short q_lds[64 * 128];
    __shared__ unsigned short k_lds[64 * 128];
    __shared__ unsigned short v_lds[128 * 64];     // [hd][key]
    __shared__ unsigned short p_lds[64 * 64];
    const int t = threadIdx.x;
    const int wave = t >> 6, lane = t & 63, quad = lane >> 4, l16 = lane & 15;
    const int bq = blockIdx.x, bh = blockIdx.y;
    const int q0 = bq << 6;
    const int b = bh >> 5;
    const unsigned short* Q  = qbuf  + (size_t)bh * S_LEN * HDIM;
    const unsigned short* Kp = kbuf  + (size_t)bh * S_LEN * HDIM;
    const unsigned short* Vp = vtbuf + (size_t)bh * HDIM * S_LEN;

    {
        int r = t >> 4, c = (t & 15) << 3;
#pragma unroll
        for (int it = 0; it < 4; it++)
            gld16(Q + (size_t)(q0 + r + (it << 4)) * HDIM + c,
                  q_lds + ((((it << 8) + (wave << 6))) << 3));
    }

    const f32x4 fz = {0.f, 0.f, 0.f, 0.f};
    f32x4 o[8];
#pragma unroll
    for (int n = 0; n < 8; n++) o[n] = fz;
    float l_i[4] = {0.f, 0.f, 0.f, 0.f};
    const float scale = 0.08838834764831845f;   // 1/sqrt(128)
    const float* mrow = mask + b * S_LEN;

    for (int kt = 0; kt <= bq; kt++) {
        const int k0 = kt << 6;
        {
            int rk = t >> 4, ck = (t & 15) << 3;
            int rv = t >> 3, cv = (t & 7) << 3;
#pragma unroll
            for (int it = 0; it < 4; it++) {
                gld16(Kp + (size_t)(k0 + rk + (it << 4)) * HDIM + ck,
                      k_lds + (((it << 8) + (wave << 6)) << 3));
                gld16(Vp + (size_t)(rv + (it << 5)) * S_LEN + k0 + cv,
                      v_lds + (((it << 8) + (wave << 6)) << 3));
            }
        }
        __syncthreads();

        f32x4 sacc[4];
#pragma unroll
        for (int j = 0; j < 4; j++) sacc[j] = fz;
        const bf16x8* qv = (const bf16x8*)q_lds;
        const bf16x8* kv = (const bf16x8*)k_lds;
#pragma unroll
        for (int kk = 0; kk < 4; kk++) {
            bf16x8 aq = qv[(((wave << 4) + l16) << 4) + (kk << 2) + quad];
#pragma unroll
            for (int j = 0; j < 4; j++) {
                bf16x8 bk = kv[((((j << 4) + l16)) << 4) + (kk << 2) + quad];
                sacc[j] = __builtin_amdgcn_mfma_f32_16x16x32_bf16(aq, bk, sacc[j], 0, 0, 0);
            }
        }

#pragma unroll
        for (int r = 0; r < 4; r++) {
            int qrow = q0 + (wave << 4) + (quad << 2) + r;
#pragma unroll
            for (int j = 0; j < 4; j++) {
                int key = k0 + (j << 4) + l16;
                float x = sacc[j][r] * scale + mrow[key];
                if (key > qrow) x -= 10000.0f;
                float p = __expf(x);
                l_i[r] += p;
                p_lds[((wave << 4) + (quad << 2) + r) * 64 + (j << 4) + l16] = f2bf(p);
            }
        }
        __syncthreads();

        const bf16x8* pvv = (const bf16x8*)p_lds;
        const bf16x8* vv = (const bf16x8*)v_lds;
#pragma unroll
        for (int ks = 0; ks < 2; ks++) {
            bf16x8 ap = pvv[(((wave << 4) + l16) << 3) + (ks << 2) + quad];
#pragma unroll
            for (int n = 0; n < 8; n++) {
                bf16x8 bvv = vv[((((n << 4) + l16)) << 3) + (ks << 2) + quad];
                o[n] = __builtin_amdgcn_mfma_f32_16x16x32_bf16(ap, bvv, o[n], 0, 0, 0);
            }
        }
        __syncthreads();
    }

#pragma unroll
    for (int r = 0; r < 4; r++) {
        float l = l_i[r];
#pragma unroll
        for (int off = 1; off < 16; off <<= 1) l += __shfl_xor(l, off);
        float inv = 1.0f / l;
        int qrow = q0 + (wave << 4) + (quad << 2) + r;
        size_t base = ((size_t)(b * S_LEN + qrow)) * HID + ((size_t)(bh & 31) << 7);
#pragma unroll
        for (int n = 0; n < 8; n++)
            ctx[base + (n << 4) + l16] = f2bf(o[n][r] * inv);
    }
}

extern "C" void kernel_launch(void* const* d_in, const int* in_sizes, int n_in,
                              void* d_out, int out_size, void* d_ws, size_t ws_size,
                              hipStream_t stream) {
    const float* x       = (const float*)d_in[0];
    const float* mask    = (const float*)d_in[1];
    const float* norm_w  = (const float*)d_in[2];
    const float* norm_b  = (const float*)d_in[3];
    const float* qkv_w   = (const float*)d_in[4];
    const float* qkv_b   = (const float*)d_in[5];
    const float* attn_ow = (const float*)d_in[6];
    float* out = (float*)d_out;

    char* ws = (char*)d_ws;
    size_t off = 0;
    auto alloc = [&](size_t bytes) {
        char* p = ws + off;
        off += (bytes + 255) & ~(size_t)255;
        return p;
    };
    unsigned short* inp_norm = (unsigned short*)alloc((size_t)2048 * HID * 2);
    unsigned short* qkv_wt   = (unsigned short*)alloc((size_t)3 * HID * HID * 2);
    unsigned short* ow_t     = (unsigned short*)alloc((size_t)HID * HID * 2);
    unsigned short* qb       = (unsigned short*)alloc((size_t)64 * S_LEN * HDIM * 2);
    unsigned short* kb       = (unsigned short*)alloc((size_t)64 * S_LEN * HDIM * 2);
    unsigned short* vt       = (unsigned short*)alloc((size_t)64 * S_LEN * HDIM * 2);
    unsigned short* ctx      = (unsigned short*)alloc((size_t)2048 * HID * 2);

    ln_kernel<<<2048, 256, 0, stream>>>(x, norm_w, norm_b, inp_norm);
    transconv<<<dim3(3 * HID / 128, HID / 64), 256, 0, stream>>>(qkv_w, qkv_wt, HID, 3 * HID);
    transconv<<<dim3(HID / 128, HID / 64), 256, 0, stream>>>(attn_ow, ow_t, HID, HID);
    gemm_qkv192<<<512, 512, 0, stream>>>(inp_norm, qkv_wt, qkv_b, qb, kb, vt);
    attn_kernel<<<dim3(16, 64), 256, 0, stream>>>(qb, kb, vt, mask, ctx);
    gemm_proj8<<<256, 512, 0, stream>>>(ctx, ow_t, out);
}

// Round 6
// 715.376 us; speedup vs baseline: 1.2284x; 1.0786x over previous
//
#include <hip/hip_runtime.h>
#include <stdint.h>

// DeepSpeed self-attention forward, bf16-MFMA implementation.
// B=2, S=1024, H=4096, NH=32, HD=128. All matmuls via mfma_f32_16x16x32_bf16.
// Round 7 (second resubmit — rounds 4/5 were GPU-acquisition timeouts, kernel
// still unmeasured): GEMMs use BK=32 K-steps, 3-buffer LDS rotation, ONE
// barrier per step, compiler-interleaved ds_read->MFMA (no manual lgkmcnt0),
// counted per-wave vmcnt with 1-step slack. Attn gets chunk-XOR swizzle on all
// four LDS buffers.

#define S_LEN 1024
#define HID   4096
#define NHEAD 32
#define HDIM  128

typedef __attribute__((ext_vector_type(8))) short bf16x8;   // 8 bf16 (4 VGPRs)
typedef __attribute__((ext_vector_type(4))) float f32x4;    // MFMA C/D
typedef __attribute__((ext_vector_type(8))) unsigned short us8; // 16B store

__device__ __forceinline__ unsigned short f2bf(float f) {
    union { float f; unsigned u; } v; v.f = f;
    unsigned r = v.u + 0x7fffu + ((v.u >> 16) & 1u);
    return (unsigned short)(r >> 16);
}

__device__ __forceinline__ void gld16(const unsigned short* g, unsigned short* l) {
    __builtin_amdgcn_global_load_lds(
        (const __attribute__((address_space(1))) void*)g,
        (__attribute__((address_space(3))) void*)l, 16, 0, 0);
}

// ---------------- LayerNorm + bf16 cast: x[2048][4096] -> inp_norm bf16 ----------
__global__ __launch_bounds__(256) void ln_kernel(const float* __restrict__ x,
        const float* __restrict__ w, const float* __restrict__ bch,
        unsigned short* __restrict__ out) {
    const int row = blockIdx.x;
    const int t = threadIdx.x;
    const float* xr = x + (size_t)row * HID;
    float4 v[4];
    float sum = 0.f, sq = 0.f;
#pragma unroll
    for (int i = 0; i < 4; i++) {
        v[i] = ((const float4*)xr)[t + (i << 8)];
        sum += v[i].x + v[i].y + v[i].z + v[i].w;
        sq  += v[i].x*v[i].x + v[i].y*v[i].y + v[i].z*v[i].z + v[i].w*v[i].w;
    }
#pragma unroll
    for (int off = 32; off; off >>= 1) {
        sum += __shfl_down(sum, off);
        sq  += __shfl_down(sq, off);
    }
    __shared__ float ssum[4], ssq[4];
    if ((t & 63) == 0) { ssum[t >> 6] = sum; ssq[t >> 6] = sq; }
    __syncthreads();
    const float s_all = ssum[0] + ssum[1] + ssum[2] + ssum[3];
    const float q_all = ssq[0] + ssq[1] + ssq[2] + ssq[3];
    const float mean = s_all * (1.f / HID);
    const float var  = q_all * (1.f / HID) - mean * mean;
    const float rstd = rsqrtf(var + 1e-5f);
    unsigned short* orow = out + (size_t)row * HID;
#pragma unroll
    for (int i = 0; i < 4; i++) {
        float4 wv = ((const float4*)w)[t + (i << 8)];
        float4 bv = ((const float4*)bch)[t + (i << 8)];
        ushort4 o;
        o.x = f2bf((v[i].x - mean) * rstd * wv.x + bv.x);
        o.y = f2bf((v[i].y - mean) * rstd * wv.y + bv.y);
        o.z = f2bf((v[i].z - mean) * rstd * wv.z + bv.z);
        o.w = f2bf((v[i].w - mean) * rstd * wv.w + bv.w);
        ((ushort4*)orow)[t + (i << 8)] = o;
    }
}

// ------------- transpose + fp32->bf16: W[K][N] -> Wt[N][K] ----------------------
__global__ __launch_bounds__(256) void transconv(const float* __restrict__ W,
        unsigned short* __restrict__ Wt, int K, int N) {
    __shared__ float tileT[128 * 65];   // [n][k], pad 65 (33.3 KB)
    const int n0 = blockIdx.x << 7, k0 = blockIdx.y << 6;
    const int t = threadIdx.x;
#pragma unroll
    for (int it = 0; it < 8; it++) {
        int idx = (it << 8) + t;
        int r = idx >> 5;            // k row 0..63
        int c4 = idx & 31;           // float4 column 0..31
        float4 v = *(const float4*)(W + (size_t)(k0 + r) * N + n0 + (c4 << 2));
        tileT[((c4 << 2) + 0) * 65 + r] = v.x;
        tileT[((c4 << 2) + 1) * 65 + r] = v.y;
        tileT[((c4 << 2) + 2) * 65 + r] = v.z;
        tileT[((c4 << 2) + 3) * 65 + r] = v.w;
    }
    __syncthreads();
#pragma unroll
    for (int it = 0; it < 4; it++) {
        int idx = (it << 8) + t;
        int n = idx >> 3;            // 0..127
        int k8 = idx & 7;            // ushort8 column, 0..7 (8 k each)
        const float* src = &tileT[n * 65 + (k8 << 3)];
        us8 o;
#pragma unroll
        for (int e = 0; e < 8; e++) o[e] = f2bf(src[e]);
        *(us8*)(Wt + (size_t)(n0 + n) * K + k0 + (k8 << 3)) = o;
    }
}

// =================================================================================
// QKV GEMM: 256x192 tile, 512 thr = 8 waves (2M x 4N), per-wave 128x48.
// K-step = 32 (128 steps). LDS: 3 rotating bufs x { A[256][32] 16KB + B[192][32]
// 12KB } = 84 KB. One barrier per step:
//   { stage step t+2 -> buf p (4 or 3 gld_lds) ; 11 ds_read_b128 from buf c ;
//     24 MFMA (compiler counted-lgkmcnt interleave) ; vmcnt(4|3) ; s_barrier }
// vmcnt forces only the 1-step-old loads -> ~1 K-step (~1500 cyc) latency slack,
// never vmcnt(0) in the loop. Single barrier is safe: reads of buf c complete
// before each wave's MFMA (lgkm), MFMA before its barrier arrival; stage targets
// buf p != c and only issues after the prior barrier.
// Swizzle (both sides): src col chunk ^= lane-derived, ds_read chunk ^ ((r>>1)&3).
// =================================================================================

#define QK_TILE(TT, CURB, PFB)                                                    \
  {                                                                               \
    int pf_ = (TT) + 2; if (pf_ > 127) pf_ = 127;                                 \
    stgA(pf_, PFB); stgB(pf_, PFB);                                               \
    bf16x8 bfv[3], af[8];                                                         \
    _Pragma("unroll") for (int jj = 0; jj < 3; jj++) bfv[jj] = ldB(CURB, jj);     \
    _Pragma("unroll") for (int ii = 0; ii < 8; ii++) af[ii] = ldA(CURB, ii);      \
    __builtin_amdgcn_s_setprio(1);                                                \
    _Pragma("unroll") for (int ii = 0; ii < 8; ii++)                              \
      _Pragma("unroll") for (int jj = 0; jj < 3; jj++)                            \
        acc[ii][jj] = __builtin_amdgcn_mfma_f32_16x16x32_bf16(                    \
            af[ii], bfv[jj], acc[ii][jj], 0, 0, 0);                               \
    __builtin_amdgcn_s_setprio(0);                                                \
    if (wave < 4) { asm volatile("s_waitcnt vmcnt(4)" ::: "memory"); }            \
    else          { asm volatile("s_waitcnt vmcnt(3)" ::: "memory"); }            \
    __builtin_amdgcn_s_barrier();                                                 \
  }

// Grid 512 = 8 bm x 64 bn = exactly 2 rounds. bm = orig&7 pins one 2MB A-panel
// per XCD L2; B streams via L3.
__global__ __launch_bounds__(512, 2) void gemm_qkv32(
        const unsigned short* __restrict__ A,
        const unsigned short* __restrict__ Bt,
        const float* __restrict__ bias,
        unsigned short* __restrict__ qb,
        unsigned short* __restrict__ kb,
        unsigned short* __restrict__ vt) {
    __shared__ unsigned short lds[43008];   // 84 KB
    const int orig = blockIdx.x;
    const int bm = orig & 7, bn = orig >> 3;      // bn 0..63
    const int t = threadIdx.x;
    const int wave = t >> 6, lane = t & 63, quad = lane >> 4, l16 = lane & 15;
    const int waveM = wave >> 2, waveN = wave & 3;

    const unsigned short* GA = A  + ((size_t)bm << 8) * HID;   // 256 rows
    const unsigned short* GB = Bt + ((size_t)bn * 192) * HID;  // 192 rows

    const int swz  = (((lane & 3) ^ ((lane >> 3) & 3)) << 3);  // src col (el)
    const int arow = lane >> 2;                                // 0..15 in granule

    // A [256][32]: 16 granules (16 rows x 32 el = 1KB), 2 per wave.
    auto stgA = [&](int tt, int buf) {
#pragma unroll
        for (int u = 0; u < 2; u++) {
            const int g = (wave << 1) + u;                     // 0..15
            gld16(GA + (size_t)((g << 4) + arow) * HID + (tt << 5) + swz,
                  lds + buf * 14336 + (g << 9));
        }
    };
    // B [192][32]: 12 granules; waves 0-3 take 2, waves 4-7 take 1.
    auto stgB = [&](int tt, int buf) {
        if (wave < 4) {
#pragma unroll
            for (int u = 0; u < 2; u++) {
                const int g = (wave << 1) + u;                 // 0..7
                gld16(GB + (size_t)((g << 4) + arow) * HID + (tt << 5) + swz,
                      lds + buf * 14336 + 8192 + (g << 9));
            }
        } else {
            const int g = wave + 4;                            // 8..11
            gld16(GB + (size_t)((g << 4) + arow) * HID + (tt << 5) + swz,
                  lds + buf * 14336 + 8192 + (g << 9));
        }
    };
    auto ldA = [&](int buf, int i) -> bf16x8 {
        const int r = (waveM << 7) + (i << 4) + l16;           // 0..255
        return ((const bf16x8*)lds)
            [((buf * 14336) >> 3) + (r << 2) + (quad ^ ((r >> 1) & 3))];
    };
    auto ldB = [&](int buf, int j) -> bf16x8 {
        const int r = waveN * 48 + (j << 4) + l16;             // 0..191
        return ((const bf16x8*)lds)
            [((buf * 14336 + 8192) >> 3) + (r << 2) + (quad ^ ((r >> 1) & 3))];
    };

    const f32x4 fz = {0.f, 0.f, 0.f, 0.f};
    f32x4 acc[8][3];
#pragma unroll
    for (int i = 0; i < 8; i++)
#pragma unroll
        for (int j = 0; j < 3; j++) acc[i][j] = fz;

    // prologue: step0 -> buf0, step1 -> buf1; force step0's (older) ops.
    stgA(0, 0); stgB(0, 0);
    stgA(1, 1); stgB(1, 1);
    if (wave < 4) { asm volatile("s_waitcnt vmcnt(4)" ::: "memory"); }
    else          { asm volatile("s_waitcnt vmcnt(3)" ::: "memory"); }
    __builtin_amdgcn_s_barrier();

    for (int tt = 0; tt < 126; tt += 3) {
        QK_TILE(tt,     0, 2)
        QK_TILE(tt + 1, 1, 0)
        QK_TILE(tt + 2, 2, 1)
    }
    QK_TILE(126, 0, 2)
    QK_TILE(127, 1, 0)
    asm volatile("s_waitcnt vmcnt(0)" ::: "memory");   // drain dummy prefetches

    // epilogue: scatter with bias (4096 % 16 == 0 -> which is frag-uniform).
#pragma unroll
    for (int ii = 0; ii < 8; ii++) {
#pragma unroll
        for (int jj = 0; jj < 3; jj++) {
#pragma unroll
            for (int r = 0; r < 4; r++) {
                int m = (bm << 8) + (waveM << 7) + (ii << 4) + (quad << 2) + r;
                int n = bn * 192 + waveN * 48 + (jj << 4) + l16;
                float v = acc[ii][jj][r] + bias[n];
                unsigned short bvv = f2bf(v);
                int bb = m >> 10, s = m & 1023;
                int which = n >> 12;           // 0=q 1=k 2=v
                int h = n & 4095, head = h >> 7, hd = h & 127;
                size_t bh = (size_t)(bb << 5) + head;
                if (which == 0)      qb[(bh * S_LEN + s) * HDIM + hd] = bvv;
                else if (which == 1) kb[(bh * S_LEN + s) * HDIM + hd] = bvv;
                else                 vt[(bh * HDIM + hd) * S_LEN + s] = bvv;
            }
        }
    }
}

// =================================================================================
// Proj GEMM: 256x128 tile, 8 waves (4M x 2N), per-wave 64x64. Same 1-barrier
// BK=32 3-buffer core; uniform 3 stage-ops/wave -> vmcnt(3).
// Grid 256 = 8 bm x 32 bn = exactly 1 round.
// =================================================================================

#define PJ_TILE(TT, CURB, PFB)                                                    \
  {                                                                               \
    int pf_ = (TT) + 2; if (pf_ > 127) pf_ = 127;                                 \
    stgA(pf_, PFB); stgB(pf_, PFB);                                               \
    bf16x8 bfv[4], af[4];                                                         \
    _Pragma("unroll") for (int jj = 0; jj < 4; jj++) bfv[jj] = ldB(CURB, jj);     \
    _Pragma("unroll") for (int ii = 0; ii < 4; ii++) af[ii] = ldA(CURB, ii);      \
    __builtin_amdgcn_s_setprio(1);                                                \
    _Pragma("unroll") for (int ii = 0; ii < 4; ii++)                              \
      _Pragma("unroll") for (int jj = 0; jj < 4; jj++)                            \
        acc[ii][jj] = __builtin_amdgcn_mfma_f32_16x16x32_bf16(                    \
            af[ii], bfv[jj], acc[ii][jj], 0, 0, 0);                               \
    __builtin_amdgcn_s_setprio(0);                                                \
    asm volatile("s_waitcnt vmcnt(3)" ::: "memory");                              \
    __builtin_amdgcn_s_barrier();                                                 \
  }

__global__ __launch_bounds__(512, 2) void gemm_proj32(
        const unsigned short* __restrict__ A,
        const unsigned short* __restrict__ Bt,
        float* __restrict__ outf) {
    __shared__ unsigned short lds[36864];   // 72 KB
    const int orig = blockIdx.x;
    const int bm = orig & 7, bn = orig >> 3;      // bn 0..31
    const int t = threadIdx.x;
    const int wave = t >> 6, lane = t & 63, quad = lane >> 4, l16 = lane & 15;
    const int waveM = wave >> 1, waveN = wave & 1;

    const unsigned short* GA = A  + ((size_t)bm << 8) * HID;   // 256 rows
    const unsigned short* GB = Bt + ((size_t)bn << 7) * HID;   // 128 rows

    const int swz  = (((lane & 3) ^ ((lane >> 3) & 3)) << 3);
    const int arow = lane >> 2;

    auto stgA = [&](int tt, int buf) {
#pragma unroll
        for (int u = 0; u < 2; u++) {
            const int g = (wave << 1) + u;                     // 0..15
            gld16(GA + (size_t)((g << 4) + arow) * HID + (tt << 5) + swz,
                  lds + buf * 12288 + (g << 9));
        }
    };
    auto stgB = [&](int tt, int buf) {
        const int g = wave;                                    // 0..7
        gld16(GB + (size_t)((g << 4) + arow) * HID + (tt << 5) + swz,
              lds + buf * 12288 + 8192 + (g << 9));
    };
    auto ldA = [&](int buf, int i) -> bf16x8 {
        const int r = (waveM << 6) + (i << 4) + l16;           // 0..255
        return ((const bf16x8*)lds)
            [((buf * 12288) >> 3) + (r << 2) + (quad ^ ((r >> 1) & 3))];
    };
    auto ldB = [&](int buf, int j) -> bf16x8 {
        const int r = (waveN << 6) + (j << 4) + l16;           // 0..127
        return ((const bf16x8*)lds)
            [((buf * 12288 + 8192) >> 3) + (r << 2) + (quad ^ ((r >> 1) & 3))];
    };

    const f32x4 fz = {0.f, 0.f, 0.f, 0.f};
    f32x4 acc[4][4];
#pragma unroll
    for (int i = 0; i < 4; i++)
#pragma unroll
        for (int j = 0; j < 4; j++) acc[i][j] = fz;

    stgA(0, 0); stgB(0, 0);
    stgA(1, 1); stgB(1, 1);
    asm volatile("s_waitcnt vmcnt(3)" ::: "memory");
    __builtin_amdgcn_s_barrier();

    for (int tt = 0; tt < 126; tt += 3) {
        PJ_TILE(tt,     0, 2)
        PJ_TILE(tt + 1, 1, 0)
        PJ_TILE(tt + 2, 2, 1)
    }
    PJ_TILE(126, 0, 2)
    PJ_TILE(127, 1, 0)
    asm volatile("s_waitcnt vmcnt(0)" ::: "memory");

#pragma unroll
    for (int ii = 0; ii < 4; ii++)
#pragma unroll
        for (int jj = 0; jj < 4; jj++)
#pragma unroll
            for (int r = 0; r < 4; r++) {
                int m = (bm << 8) + (waveM << 6) + (ii << 4) + (quad << 2) + r;
                int n = (bn << 7) + (waveN << 6) + (jj << 4) + l16;
                outf[((size_t)m << 12) + n] = acc[ii][jj][r];
            }
}

// ---------------- flash attention: 64-query tile per block, causal ---------------
// Chunk-XOR swizzle on q/k/v (pre-swizzled global src, gld_lds dest linear) and
// p (swizzled VALU writes); matching XOR on every ds_read. Removes the 2x
// LDS-read serialization (row strides 256B/128B put each quad's 16 lanes on the
// same 4 banks without it).
__global__ __launch_bounds__(256) void attn_kernel(
        const unsigned short* __restrict__ qbuf,   // [64][1024][128]
        const unsigned short* __restrict__ kbuf,   // [64][1024][128]
        const unsigned short* __restrict__ vtbuf,  // [64][128][1024]
        const float* __restrict__ mask,            // [2][1024]
        unsigned short* __restrict__ ctx) {        // [2048][4096]
    __shared__ unsigned short q_lds[64 * 128];
    __shared__ unsigned short k_lds[64 * 128];
    __shared__ unsigned short v_lds[128 * 64];     // [hd][key]
    __shared__ unsigned short p_lds[64 * 64];
    const int t = threadIdx.x;
    const int wave = t >> 6, lane = t & 63, quad = lane >> 4, l16 = lane & 15;
    const int bq = blockIdx.x, bh = blockIdx.y;
    const int q0 = bq << 6;
    const int b = bh >> 5;
    const unsigned short* Q  = qbuf  + (size_t)bh * S_LEN * HDIM;
    const unsigned short* Kp = kbuf  + (size_t)bh * S_LEN * HDIM;
    const unsigned short* Vp = vtbuf + (size_t)bh * HDIM * S_LEN;

    {   // stage Q tile (64x128), src chunk pre-swizzled with row&7
        int r = t >> 4;
        int c = (((t & 15) ^ ((t >> 4) & 7)) << 3);
#pragma unroll
        for (int it = 0; it < 4; it++)
            gld16(Q + (size_t)(q0 + r + (it << 4)) * HDIM + c,
                  q_lds + ((((it << 8) + (wave << 6))) << 3));
    }

    const f32x4 fz = {0.f, 0.f, 0.f, 0.f};
    f32x4 o[8];
#pragma unroll
    for (int n = 0; n < 8; n++) o[n] = fz;
    float l_i[4] = {0.f, 0.f, 0.f, 0.f};
    const float scale = 0.08838834764831845f;   // 1/sqrt(128)
    const float* mrow = mask + b * S_LEN;

    for (int kt = 0; kt <= bq; kt++) {
        const int k0 = kt << 6;
        {   // stage K (64x128) and V^T (128x64), pre-swizzled src
            int rk = t >> 4, ck = (((t & 15) ^ ((t >> 4) & 7)) << 3);
            int rv = t >> 3, cv = (((t & 7) ^ ((t >> 3) & 7)) << 3);
#pragma unroll
            for (int it = 0; it < 4; it++) {
                gld16(Kp + (size_t)(k0 + rk + (it << 4)) * HDIM + ck,
                      k_lds + (((it << 8) + (wave << 6)) << 3));
                gld16(Vp + (size_t)(rv + (it << 5)) * S_LEN + k0 + cv,
                      v_lds + (((it << 8) + (wave << 6)) << 3));
            }
        }
        __syncthreads();

        // QK^T: wave handles 16-query strip, 4 key n-tiles
        f32x4 sacc[4];
#pragma unroll
        for (int j = 0; j < 4; j++) sacc[j] = fz;
        const bf16x8* qv = (const bf16x8*)q_lds;
        const bf16x8* kv = (const bf16x8*)k_lds;
#pragma unroll
        for (int kk = 0; kk < 4; kk++) {
            bf16x8 aq = qv[(((wave << 4) + l16) << 4) + (((kk << 2) + quad) ^ (l16 & 7))];
#pragma unroll
            for (int j = 0; j < 4; j++) {
                bf16x8 bk = kv[((((j << 4) + l16)) << 4) + (((kk << 2) + quad) ^ (l16 & 7))];
                sacc[j] = __builtin_amdgcn_mfma_f32_16x16x32_bf16(aq, bk, sacc[j], 0, 0, 0);
            }
        }

        // softmax numerator: p = exp(score); accumulate row-sum per lane
#pragma unroll
        for (int r = 0; r < 4; r++) {
            int prow = (wave << 4) + (quad << 2) + r;
            int qrow = q0 + prow;
#pragma unroll
            for (int j = 0; j < 4; j++) {
                int key = k0 + (j << 4) + l16;
                float x = sacc[j][r] * scale + mrow[key];
                if (key > qrow) x -= 10000.0f;    // causal: exp underflows to 0
                float p = __expf(x);
                l_i[r] += p;
                int pc = (j << 1) + (l16 >> 3);               // chunk 0..7
                p_lds[(prow << 6) + ((pc ^ (prow & 7)) << 3) + (l16 & 7)] = f2bf(p);
            }
        }
        __syncthreads();

        // PV: O[16 x 128] += P[16 x 64] * V[64 x 128]
        const bf16x8* pvv = (const bf16x8*)p_lds;
        const bf16x8* vv = (const bf16x8*)v_lds;
#pragma unroll
        for (int ks = 0; ks < 2; ks++) {
            bf16x8 ap = pvv[(((wave << 4) + l16) << 3) + (((ks << 2) + quad) ^ (l16 & 7))];
#pragma unroll
            for (int n = 0; n < 8; n++) {
                bf16x8 bvv = vv[((((n << 4) + l16)) << 3) + (((ks << 2) + quad) ^ (l16 & 7))];
                o[n] = __builtin_amdgcn_mfma_f32_16x16x32_bf16(ap, bvv, o[n], 0, 0, 0);
            }
        }
        __syncthreads();
    }

    // epilogue: reduce l across the 16 lanes sharing each row, then normalize
#pragma unroll
    for (int r = 0; r < 4; r++) {
        float l = l_i[r];
#pragma unroll
        for (int off = 1; off < 16; off <<= 1) l += __shfl_xor(l, off);
        float inv = 1.0f / l;
        int qrow = q0 + (wave << 4) + (quad << 2) + r;
        size_t base = ((size_t)(b * S_LEN + qrow)) * HID + ((size_t)(bh & 31) << 7);
#pragma unroll
        for (int n = 0; n < 8; n++)
            ctx[base + (n << 4) + l16] = f2bf(o[n][r] * inv);
    }
}

extern "C" void kernel_launch(void* const* d_in, const int* in_sizes, int n_in,
                              void* d_out, int out_size, void* d_ws, size_t ws_size,
                              hipStream_t stream) {
    const float* x       = (const float*)d_in[0];
    const float* mask    = (const float*)d_in[1];
    const float* norm_w  = (const float*)d_in[2];
    const float* norm_b  = (const float*)d_in[3];
    const float* qkv_w   = (const float*)d_in[4];
    const float* qkv_b   = (const float*)d_in[5];
    const float* attn_ow = (const float*)d_in[6];
    float* out = (float*)d_out;

    char* ws = (char*)d_ws;
    size_t off = 0;
    auto alloc = [&](size_t bytes) {
        char* p = ws + off;
        off += (bytes + 255) & ~(size_t)255;
        return p;
    };
    unsigned short* inp_norm = (unsigned short*)alloc((size_t)2048 * HID * 2);
    unsigned short* qkv_wt   = (unsigned short*)alloc((size_t)3 * HID * HID * 2);
    unsigned short* ow_t     = (unsigned short*)alloc((size_t)HID * HID * 2);
    unsigned short* qb       = (unsigned short*)alloc((size_t)64 * S_LEN * HDIM * 2);
    unsigned short* kb       = (unsigned short*)alloc((size_t)64 * S_LEN * HDIM * 2);
    unsigned short* vt       = (unsigned short*)alloc((size_t)64 * S_LEN * HDIM * 2);
    unsigned short* ctx      = (unsigned short*)alloc((size_t)2048 * HID * 2);

    ln_kernel<<<2048, 256, 0, stream>>>(x, norm_w, norm_b, inp_norm);
    transconv<<<dim3(3 * HID / 128, HID / 64), 256, 0, stream>>>(qkv_w, qkv_wt, HID, 3 * HID);
    transconv<<<dim3(HID / 128, HID / 64), 256, 0, stream>>>(attn_ow, ow_t, HID, HID);
    gemm_qkv32<<<512, 512, 0, stream>>>(inp_norm, qkv_wt, qkv_b, qb, kb, vt);
    attn_kernel<<<dim3(16, 64), 256, 0, stream>>>(qb, kb, vt, mask, ctx);
    gemm_proj32<<<256, 512, 0, stream>>>(ctx, ow_t, out);
}